// Round 9
// baseline (465.961 us; speedup 1.0000x reference)
//
#include <hip/hip_runtime.h>

#define NN 32768
#define NE 131072
#define NB 512
#define SL 1000

using bf16x8 = __attribute__((ext_vector_type(8))) short;
using f32x4  = __attribute__((ext_vector_type(4))) float;

static __device__ __forceinline__ unsigned short f2b(float f) {
  union { float f; unsigned u; } x; x.f = f;
  unsigned r = x.u + 0x7fffu + ((x.u >> 16) & 1u);  // RNE
  return (unsigned short)(r >> 16);
}

static __device__ __forceinline__ void bn_from_raw(float sum, float ssq, float g, float b,
                                                   float& sc, float& sh) {
  float m = sum / 32768.f;
  float v = ssq / 32768.f - m * m;
  sc = g * rsqrtf(v + 1e-5f);
  sh = b - m * sc;
}

// ---------------- fused degree + conv-weight prep + conv1 table ----------------
__global__ void k_degprep(const int* __restrict__ dst, int* __restrict__ degi,
                          const float* __restrict__ emb, const float* __restrict__ ck1,
                          const float* __restrict__ ck2, const float* __restrict__ ck3,
                          unsigned short* __restrict__ wt2, unsigned short* __restrict__ wt3,
                          float* __restrict__ e1) {
  int gid = blockIdx.x * 256 + threadIdx.x;
  atomicAdd(&degi[dst[gid]], 1);
  int idx = gid;
  if (idx < 12288) {
    int i = idx;
    int kt = i >> 11, co = (i >> 5) & 63, ci = i & 31;
    wt2[i] = f2b(ck2[co * 192 + ci * 6 + kt]);
  } else if (idx < 12288 + 49152) {
    int i = idx - 12288;
    int kt = i / 6144, co = (i >> 6) % 96, ci = i & 63;
    wt3[i] = f2b(ck3[co * 512 + ci * 8 + kt]);
  } else if (idx < 12288 + 49152 + 3328) {
    int i = idx - 61440;                     // i = t*128 + kt*32 + co
    int t = i >> 7, kt = (i >> 5) & 3, co = i & 31;
    const float* er = emb + t * 128;
    float s = 0.f;
#pragma unroll 4
    for (int ci = 0; ci < 128; ++ci) s += er[ci] * ck1[co * 512 + ci * 4 + kt];
    e1[i] = s;
  }
}

__global__ void k_scan(const int* __restrict__ degi, int* __restrict__ base,
                       int* __restrict__ cursor, float* __restrict__ dis) {
  __shared__ int part[1024];
  int tid = threadIdx.x;
  int v[32];
  int s = 0;
  int lo = tid * 32;
#pragma unroll
  for (int i = 0; i < 32; ++i) { v[i] = degi[lo + i]; s += v[i]; }
  part[tid] = s;
  __syncthreads();
  for (int off = 1; off < 1024; off <<= 1) {
    int val = (tid >= off) ? part[tid - off] : 0;
    __syncthreads();
    part[tid] += val;
    __syncthreads();
  }
  int run = (tid > 0) ? part[tid - 1] : 0;
#pragma unroll
  for (int i = 0; i < 32; ++i) {
    base[lo + i] = run;
    cursor[lo + i] = run;
    dis[lo + i] = rsqrtf(1.0f + (float)v[i]);
    run += v[i];
  }
  if (tid == 1023) base[NN] = run;
}

__global__ void k_fill(const int* __restrict__ src, const int* __restrict__ dst,
                       int* __restrict__ cursor, unsigned short* __restrict__ csr_src, int E) {
  int e = blockIdx.x * 256 + threadIdx.x;
  if (e < E) {
    int d = dst[e];
    int pos = atomicAdd(&cursor[d], 1);
    csr_src[pos] = (unsigned short)src[e];
  }
}

// ---------------- L1a: aggregate x over graph, thread-per-node, 64-thread blocks ----------------
// Same per-node edge loop as the old k_gfc1s phase 1 (bitwise-identical aggregates), but
// 512 blocks instead of 128 -> all 256 CUs active for the latency-bound edge walk.
__launch_bounds__(64)
__global__ void k_agg5(const float* __restrict__ x, const float* __restrict__ dis,
                       const int* __restrict__ base, const unsigned short* __restrict__ csr_src,
                       float* __restrict__ a5g) {
  int n = blockIdx.x * 64 + threadIdx.x;
  float dn = dis[n];
  float s2 = dn * dn;
  const float* xn = x + (long)n * 5;
  float a0 = xn[0] * s2, a1 = xn[1] * s2, a2 = xn[2] * s2, a3 = xn[3] * s2, a4 = xn[4] * s2;
  int b0 = base[n], b1 = base[n + 1];
  int sNext = (b0 < b1) ? csr_src[b0] : 0;
  for (int j = b0; j < b1; ++j) {
    int s = sNext;
    if (j + 1 < b1) sNext = csr_src[j + 1];
    float coef = dis[s] * dn;
    const float* xs = x + (long)s * 5;
    a0 += xs[0] * coef; a1 += xs[1] * coef; a2 += xs[2] * coef;
    a3 += xs[3] * coef; a4 += xs[4] * coef;
  }
  float* o = a5g + (long)n * 5;
  o[0] = a0; o[1] = a1; o[2] = a2; o[3] = a3; o[4] = a4;
}

// ---------------- L1b: 5->64 fc + fused stats (2048 blocks, 16 nodes/block) ----------------
__launch_bounds__(256)
__global__ void k_fc5s(const float* __restrict__ a5g, const float* __restrict__ W1,
                       float* __restrict__ out, float* __restrict__ st) {
  __shared__ float sW[5][64];
  __shared__ float red[16][64];
  int tid = threadIdx.x;
  for (int i = tid; i < 320; i += 256) sW[i >> 6][i & 63] = W1[i];
  __syncthreads();
  int grp = tid >> 4;                 // node-in-block 0..15
  int co = (tid & 15) * 4;
  long n = (long)blockIdx.x * 16 + grp;
  float a[5];
#pragma unroll
  for (int ci = 0; ci < 5; ++ci) a[ci] = a5g[n * 5 + ci];
  float4 acc = {0.f, 0.f, 0.f, 0.f};
#pragma unroll
  for (int ci = 0; ci < 5; ++ci) {
    float av = a[ci];
    acc.x += av * sW[ci][co];     acc.y += av * sW[ci][co + 1];
    acc.z += av * sW[ci][co + 2]; acc.w += av * sW[ci][co + 3];
  }
  *(float4*)&out[n * 64 + co] = acc;
  *(float4*)&red[grp][co] = acc;
  __syncthreads();
  if (tid < 64) {
    float t = 0.f;
#pragma unroll
    for (int s = 0; s < 16; ++s) t += red[s][tid];
    atomicAdd(&st[tid], t);
  }
  __syncthreads();
  float4 ss;
  ss.x = acc.x * acc.x; ss.y = acc.y * acc.y; ss.z = acc.z * acc.z; ss.w = acc.w * acc.w;
  *(float4*)&red[grp][co] = ss;
  __syncthreads();
  if (tid < 64) {
    float t = 0.f;
#pragma unroll
    for (int s = 0; s < 16; ++s) t += red[s][tid];
    atomicAdd(&st[64 + tid], t);
  }
}

// ---------------- gather with BN-on-load (raw-sum stats), index prefetch ----------------
template<int C>
__launch_bounds__(256)
__global__ void k_gbngather(const float* __restrict__ in, const float* __restrict__ dis,
                            const int* __restrict__ base, const unsigned short* __restrict__ csr_src,
                            const float* __restrict__ st, const float* __restrict__ g,
                            const float* __restrict__ bt, float* __restrict__ out) {
  constexpr int TPN = C / 4;
  int t = blockIdx.x * 256 + threadIdx.x;
  int n = t / TPN;
  int c = (t % TPN) * 4;
  float4 sum4 = *(const float4*)&st[c];
  float4 ssq4 = *(const float4*)&st[C + c];
  float4 gg = *(const float4*)&g[c];
  float4 bb = *(const float4*)&bt[c];
  float4 sc4, sh4;
  bn_from_raw(sum4.x, ssq4.x, gg.x, bb.x, sc4.x, sh4.x);
  bn_from_raw(sum4.y, ssq4.y, gg.y, bb.y, sc4.y, sh4.y);
  bn_from_raw(sum4.z, ssq4.z, gg.z, bb.z, sc4.z, sh4.z);
  bn_from_raw(sum4.w, ssq4.w, gg.w, bb.w, sc4.w, sh4.w);
  float dn = dis[n];
  float s2 = dn * dn;
  float4 a = *(const float4*)&in[(long)n * C + c];
  float4 acc;
  acc.x = fmaxf(a.x * sc4.x + sh4.x, 0.f) * s2;
  acc.y = fmaxf(a.y * sc4.y + sh4.y, 0.f) * s2;
  acc.z = fmaxf(a.z * sc4.z + sh4.z, 0.f) * s2;
  acc.w = fmaxf(a.w * sc4.w + sh4.w, 0.f) * s2;
  int b0 = base[n], b1 = base[n + 1];
  int sNext = (b0 < b1) ? csr_src[b0] : 0;
  for (int j = b0; j < b1; ++j) {
    int s = sNext;
    if (j + 1 < b1) sNext = csr_src[j + 1];
    float coef = dis[s] * dn;
    float4 vv = *(const float4*)&in[(long)s * C + c];
    acc.x += fmaxf(vv.x * sc4.x + sh4.x, 0.f) * coef;
    acc.y += fmaxf(vv.y * sc4.y + sh4.y, 0.f) * coef;
    acc.z += fmaxf(vv.z * sc4.z + sh4.z, 0.f) * coef;
    acc.w += fmaxf(vv.w * sc4.w + sh4.w, 0.f) * coef;
  }
  *(float4*)&out[(long)n * C + c] = acc;
}

// ---------------- register-tiled dense layer with fused stats (GNN fc layers) ----------------
template<int C_OUT, int K, int TN, bool RELU, bool BIAS, bool STATS>
__launch_bounds__(256)
__global__ void k_fc4(const float* __restrict__ in, const float* __restrict__ W,
                      const float* __restrict__ bias, float* __restrict__ out,
                      float* __restrict__ st, int N) {
  constexpr int CO4 = C_OUT / 4;
  constexpr int GPB = 256 / CO4;
  int g = blockIdx.x * GPB + threadIdx.x / CO4;
  long n0 = (long)g * TN;
  if (!STATS && n0 >= N) return;
  int co = (threadIdx.x % CO4) * 4;
  float4 acc[TN];
  float4 b4 = {0.f, 0.f, 0.f, 0.f};
  if (BIAS) b4 = *(const float4*)&bias[co];
#pragma unroll
  for (int t = 0; t < TN; ++t) acc[t] = b4;
  for (int ci = 0; ci < K; ci += 4) {
    float4 w0 = *(const float4*)&W[(long)(ci + 0) * C_OUT + co];
    float4 w1 = *(const float4*)&W[(long)(ci + 1) * C_OUT + co];
    float4 w2 = *(const float4*)&W[(long)(ci + 2) * C_OUT + co];
    float4 w3 = *(const float4*)&W[(long)(ci + 3) * C_OUT + co];
#pragma unroll
    for (int t = 0; t < TN; ++t) {
      float4 a = *(const float4*)&in[(n0 + t) * K + ci];
      acc[t].x += a.x * w0.x; acc[t].y += a.x * w0.y; acc[t].z += a.x * w0.z; acc[t].w += a.x * w0.w;
      acc[t].x += a.y * w1.x; acc[t].y += a.y * w1.y; acc[t].z += a.y * w1.z; acc[t].w += a.y * w1.w;
      acc[t].x += a.z * w2.x; acc[t].y += a.z * w2.y; acc[t].z += a.z * w2.z; acc[t].w += a.z * w2.w;
      acc[t].x += a.w * w3.x; acc[t].y += a.w * w3.y; acc[t].z += a.w * w3.z; acc[t].w += a.w * w3.w;
    }
  }
  float4 s4 = {0.f, 0.f, 0.f, 0.f}, ss4 = {0.f, 0.f, 0.f, 0.f};
#pragma unroll
  for (int t = 0; t < TN; ++t) {
    float4 o = acc[t];
    if (RELU) {
      o.x = fmaxf(o.x, 0.f); o.y = fmaxf(o.y, 0.f);
      o.z = fmaxf(o.z, 0.f); o.w = fmaxf(o.w, 0.f);
    }
    *(float4*)&out[(n0 + t) * C_OUT + co] = o;
    if (STATS) {
      s4.x += o.x; s4.y += o.y; s4.z += o.z; s4.w += o.w;
      ss4.x += o.x * o.x; ss4.y += o.y * o.y;
      ss4.z += o.z * o.z; ss4.w += o.w * o.w;
    }
  }
  if (STATS) {
    __shared__ float red2[GPB][C_OUT];
    int grp = threadIdx.x / CO4;
    *(float4*)&red2[grp][co] = s4;
    __syncthreads();
    if (threadIdx.x < C_OUT) {
      float t = 0.f;
#pragma unroll
      for (int s = 0; s < GPB; ++s) t += red2[s][threadIdx.x];
      atomicAdd(&st[threadIdx.x], t);
    }
    __syncthreads();
    *(float4*)&red2[grp][co] = ss4;
    __syncthreads();
    if (threadIdx.x < C_OUT) {
      float t = 0.f;
#pragma unroll
      for (int s = 0; s < GPB; ++s) t += red2[s][threadIdx.x];
      atomicAdd(&st[C_OUT + threadIdx.x], t);
    }
  }
}

// ---------------- GNN mean-pool (verbatim R5 pool-block body, standalone) ----------------
__launch_bounds__(128)
__global__ void k_pool(const float* __restrict__ agg, const float* __restrict__ st3,
                       const float* __restrict__ g3, const float* __restrict__ bt3,
                       const int* __restrict__ batch, float* __restrict__ outmax) {
  __shared__ int s_lo, s_hi;
  int b = blockIdx.x, tid = threadIdx.x;
  if (tid == 0) {
    int lo = 0, hi = NN;
    while (lo < hi) { int m = (lo + hi) >> 1; if (batch[m] < b) lo = m + 1; else hi = m; }
    s_lo = lo;
    hi = NN;
    while (lo < hi) { int m = (lo + hi) >> 1; if (batch[m] <= b) lo = m + 1; else hi = m; }
    s_hi = lo;
  }
  __syncthreads();
  {
    int lo = s_lo, hi = s_hi, c = tid;
    float sc, sh;
    bn_from_raw(st3[c], st3[128 + c], g3[c], bt3[c], sc, sh);
    float s = 0.f;
    for (int n = lo; n < hi; ++n) s += fmaxf(agg[(long)n * 128 + c] * sc + sh, 0.f);
    outmax[b * 224 + c] = s / fmaxf((float)(hi - lo), 1.0f);
  }
}

// ---------------- fused regressor: per-sample 224 -> 512 -> 256 -> 1 (R5 form) ----------------
__launch_bounds__(256)
__global__ void k_reg(const float* __restrict__ cbuf,
                      const float* __restrict__ fw1, const float* __restrict__ fb1,
                      const float* __restrict__ fw2, const float* __restrict__ fb2,
                      const float* __restrict__ fw3, const float* __restrict__ fb3,
                      float* __restrict__ out) {
  __shared__ float cin[224];
  __shared__ float h1[512];
  __shared__ float h2[256];
  __shared__ float red[4];
  int b = blockIdx.x, t = threadIdx.x;
  if (t < 224) cin[t] = cbuf[b * 224 + t];
  __syncthreads();
  {
    float a0 = fb1[t], a1 = fb1[t + 256];
    for (int ci = 0; ci < 224; ++ci) {
      float av = cin[ci];
      a0 += av * fw1[ci * 512 + t];
      a1 += av * fw1[ci * 512 + t + 256];
    }
    h1[t] = fmaxf(a0, 0.f);
    h1[t + 256] = fmaxf(a1, 0.f);
  }
  __syncthreads();
  {
    float a = fb2[t];
    for (int ci = 0; ci < 512; ++ci) a += h1[ci] * fw2[ci * 256 + t];
    h2[t] = fmaxf(a, 0.f);
  }
  __syncthreads();
  {
    float p = h2[t] * fw3[t];
#pragma unroll
    for (int off = 32; off > 0; off >>= 1) p += __shfl_down(p, off, 64);
    if ((t & 63) == 0) red[t >> 6] = p;
    __syncthreads();
    if (t == 0) out[b] = red[0] + red[1] + red[2] + red[3] + fb3[0];
  }
}

// ---------------- merged: protein conv tiles (blocks 0..4095) + gather128 (4096..8191) ----
// Proven in R8: conv dur unchanged at ~111us while absorbing all of gather128's work
// (FETCH 10.7->37.5 GB). Conv body verbatim R5; gather body verbatim k_gbngather<128>.
__launch_bounds__(256, 3)
__global__ void conv_mfma(const int* __restrict__ seq, const float* __restrict__ e1g,
                          const float* __restrict__ cb1,
                          const unsigned short* __restrict__ wt2g, const float* __restrict__ cb2,
                          const unsigned short* __restrict__ wt3g, const float* __restrict__ cb3,
                          const float* __restrict__ gin, const float* __restrict__ dis,
                          const int* __restrict__ base, const unsigned short* __restrict__ csr_src,
                          const float* __restrict__ st2, const float* __restrict__ g2,
                          const float* __restrict__ bt2, float* __restrict__ gout,
                          float* __restrict__ outmax) {
  __shared__ __align__(16) unsigned short s_w[12288];
  __shared__ __align__(16) unsigned short s_c1[4864];   // 152 rows x 32 (XOR 16B-slot swizzle, key row&3)
  __shared__ __align__(16) unsigned short s_c2[9216];   // 144 rows x 64 (XOR 16B-slot swizzle, key row&7)
  __shared__ int s_tok[152];
  __shared__ int s_max[96];

  int tid = threadIdx.x;

  if (blockIdx.x >= 4096) {  // ---------------- gather128 part ----------------
    int t = (blockIdx.x - 4096) * 256 + tid;
    int n = t / 32;
    int c = (t % 32) * 4;
    float4 sum4 = *(const float4*)&st2[c];
    float4 ssq4 = *(const float4*)&st2[128 + c];
    float4 gg = *(const float4*)&g2[c];
    float4 bb = *(const float4*)&bt2[c];
    float4 sc4, sh4;
    bn_from_raw(sum4.x, ssq4.x, gg.x, bb.x, sc4.x, sh4.x);
    bn_from_raw(sum4.y, ssq4.y, gg.y, bb.y, sc4.y, sh4.y);
    bn_from_raw(sum4.z, ssq4.z, gg.z, bb.z, sc4.z, sh4.z);
    bn_from_raw(sum4.w, ssq4.w, gg.w, bb.w, sc4.w, sh4.w);
    float dn = dis[n];
    float s2 = dn * dn;
    float4 a = *(const float4*)&gin[(long)n * 128 + c];
    float4 acc;
    acc.x = fmaxf(a.x * sc4.x + sh4.x, 0.f) * s2;
    acc.y = fmaxf(a.y * sc4.y + sh4.y, 0.f) * s2;
    acc.z = fmaxf(a.z * sc4.z + sh4.z, 0.f) * s2;
    acc.w = fmaxf(a.w * sc4.w + sh4.w, 0.f) * s2;
    int b0 = base[n], b1 = base[n + 1];
    int sNext = (b0 < b1) ? csr_src[b0] : 0;
    for (int j = b0; j < b1; ++j) {
      int s = sNext;
      if (j + 1 < b1) sNext = csr_src[j + 1];
      float coef = dis[s] * dn;
      float4 vv = *(const float4*)&gin[(long)s * 128 + c];
      acc.x += fmaxf(vv.x * sc4.x + sh4.x, 0.f) * coef;
      acc.y += fmaxf(vv.y * sc4.y + sh4.y, 0.f) * coef;
      acc.z += fmaxf(vv.z * sc4.z + sh4.z, 0.f) * coef;
      acc.w += fmaxf(vv.w * sc4.w + sh4.w, 0.f) * coef;
    }
    *(float4*)&gout[(long)n * 128 + c] = acc;
    return;
  }

  // ---------------- conv tile part (verbatim R5 body) ----------------
  int tile = blockIdx.x >> 9;
  int b = blockIdx.x & 511;
  int t0 = tile * 128;

  if (tid < 96) s_max[tid] = 0;
  if (tid < 152) {
    int p = t0 - 6 + tid;
    s_tok[tid] = (p >= 0 && p < SL) ? seq[b * SL + p] : 0;
  }
  // zero s_c1 rows 144..151 (read-ahead region of conv2's 9th tile)
  if (tid < 128) ((int*)(s_c1 + 144 * 32))[tid] = 0;

  // phase 0: stage conv2 weights (full 384 rows x 32)
  {
#pragma unroll
    for (int c = 0; c < 6; ++c) {
      int ch = c * 256 + tid;
      int row = ch >> 2;
      *(bf16x8*)&s_w[row * 32 + (((row ^ ch) & 3) << 3)] = *(const bf16x8*)(wt2g + ch * 8);
    }
  }
  __syncthreads();  // barrier 1: s_tok + s_w(conv2) + c1 tail zeros ready

  int lane = tid & 63, wave = tid >> 6;
  int l15 = lane & 15, quad = lane >> 4;

  // ---- conv1 via table: rows 0..143, 32 ch each; 2 threads per row (16 ch per thread)
  {
    bool edge = (tile == 0) || (tile == 7);
#pragma unroll
    for (int pass = 0; pass < 2; ++pass) {
      int m = (pass == 0) ? (tid >> 1) : (128 + (tid >> 1));
      bool act = (pass == 0) || (tid < 32);
      if (act) {
        int co0 = (tid & 1) * 16;
        f32x4 a4[4];
#pragma unroll
        for (int q = 0; q < 4; ++q) a4[q] = *(const f32x4*)&cb1[co0 + q * 4];
#pragma unroll
        for (int kt = 0; kt < 4; ++kt) {
          const float* e = e1g + s_tok[m + kt] * 128 + kt * 32 + co0;
#pragma unroll
          for (int q = 0; q < 4; ++q) {
            f32x4 v = *(const f32x4*)&e[q * 4];
            a4[q][0] += v[0]; a4[q][1] += v[1]; a4[q][2] += v[2]; a4[q][3] += v[3];
          }
        }
        int l1 = t0 - 5 + m;
        bool ok = !edge || (l1 >= 0 && l1 < 999);   // uniform per thread (m fixed)
#pragma unroll
        for (int q = 0; q < 4; ++q) {
#pragma unroll
          for (int e2 = 0; e2 < 4; e2 += 2) {
            int co = co0 + q * 4 + e2;
            unsigned lo = ok ? (unsigned)f2b(fmaxf(a4[q][e2], 0.f)) : 0u;
            unsigned hi = ok ? (unsigned)f2b(fmaxf(a4[q][e2 + 1], 0.f)) : 0u;
            *(unsigned*)&s_c1[m * 32 + ((((co >> 3) ^ m) & 3) << 3) + (co & 7)] = lo | (hi << 16);
          }
        }
      }
    }
  }
  __syncthreads();  // barrier 2: s_c1 ready

  // ---- conv2: A from s_c1, B from s_w (staged phase 0)
  {
    int mt0 = wave, mt1 = wave + 4;
    f32x4 acc[2][4];
#pragma unroll
    for (int nt = 0; nt < 4; ++nt) {
      float bv = cb2[nt * 16 + l15];
      acc[0][nt] = (f32x4){bv, bv, bv, bv};
      acc[1][nt] = (f32x4){bv, bv, bv, bv};
    }
    for (int kt = 0; kt < 6; ++kt) {
      int r0 = mt0 * 16 + l15 + kt, r1 = mt1 * 16 + l15 + kt;
      bf16x8 a0 = *(const bf16x8*)&s_c1[r0 * 32 + (((quad ^ r0) & 3) << 3)];
      bf16x8 a1 = *(const bf16x8*)&s_c1[r1 * 32 + (((quad ^ r1) & 3) << 3)];
#pragma unroll
      for (int nt = 0; nt < 4; ++nt) {
        int wr = kt * 64 + nt * 16 + l15;
        bf16x8 bf = *(const bf16x8*)&s_w[wr * 32 + (((quad ^ wr) & 3) << 3)];
        acc[0][nt] = __builtin_amdgcn_mfma_f32_16x16x32_bf16(a0, bf, acc[0][nt], 0, 0, 0);
        acc[1][nt] = __builtin_amdgcn_mfma_f32_16x16x32_bf16(a1, bf, acc[1][nt], 0, 0, 0);
      }
    }
#pragma unroll
    for (int mb = 0; mb < 2; ++mb) {
      int mt = mb ? mt1 : mt0;
#pragma unroll
      for (int nt = 0; nt < 4; ++nt) {
        int co = nt * 16 + l15;
#pragma unroll
        for (int r = 0; r < 4; ++r) {
          int m = mt * 16 + quad * 4 + r;
          int l2 = t0 - 3 + m;
          unsigned short hv = f2b(fmaxf(acc[mb][nt][r], 0.f));
          s_c2[m * 64 + ((((co >> 3) ^ m) & 7) << 3) + (co & 7)] = (l2 >= 0 && l2 < 998) ? hv : (unsigned short)0;
        }
      }
    }
    if (wave == 0) {
      f32x4 acc8[4];
#pragma unroll
      for (int nt = 0; nt < 4; ++nt) {
        float bv = cb2[nt * 16 + l15];
        acc8[nt] = (f32x4){bv, bv, bv, bv};
      }
      for (int kt = 0; kt < 6; ++kt) {
        int r0 = 128 + l15 + kt;
        bf16x8 a0 = *(const bf16x8*)&s_c1[r0 * 32 + (((quad ^ r0) & 3) << 3)];
#pragma unroll
        for (int nt = 0; nt < 4; ++nt) {
          int wr = kt * 64 + nt * 16 + l15;
          bf16x8 bf = *(const bf16x8*)&s_w[wr * 32 + (((quad ^ wr) & 3) << 3)];
          acc8[nt] = __builtin_amdgcn_mfma_f32_16x16x32_bf16(a0, bf, acc8[nt], 0, 0, 0);
        }
      }
#pragma unroll
      for (int nt = 0; nt < 4; ++nt) {
        int co = nt * 16 + l15;
#pragma unroll
        for (int r = 0; r < 4; ++r) {
          int m = 128 + quad * 4 + r;
          int l2 = t0 - 3 + m;
          unsigned short hv = f2b(fmaxf(acc8[nt][r], 0.f));
          s_c2[m * 64 + ((((co >> 3) ^ m) & 7) << 3) + (co & 7)] = (l2 >= 0 && l2 < 998) ? hv : (unsigned short)0;
        }
      }
    }
  }

  // ---- stage conv3 kt=0 weights (dbuf 2 x [96][64])
  {
    bf16x8 w3t[3];
#pragma unroll
    for (int c = 0; c < 3; ++c) w3t[c] = *(const bf16x8*)(wt3g + (c * 256 + tid) * 8);
    __syncthreads();  // conv2 compute read s_w/s_c2 with no trailing barrier
#pragma unroll
    for (int c = 0; c < 3; ++c) {
      int ch = c * 256 + tid;
      int row = ch >> 3;
      *(bf16x8*)&s_w[row * 64 + (((row ^ ch) & 7) << 3)] = w3t[c];
    }
    __syncthreads();
  }

  // ---- conv3: kt double-buffered weights + fused max-pool
  {
    int mt0 = wave, mt1 = wave + 4;
    f32x4 acc[2][6];
#pragma unroll
    for (int nt = 0; nt < 6; ++nt) {
      float bv = cb3[nt * 16 + l15];
      acc[0][nt] = (f32x4){bv, bv, bv, bv};
      acc[1][nt] = (f32x4){bv, bv, bv, bv};
    }
    for (int kt = 0; kt < 8; ++kt) {
      bf16x8 w3t[3];
      if (kt < 7) {
#pragma unroll
        for (int c = 0; c < 3; ++c)
          w3t[c] = *(const bf16x8*)(wt3g + ((kt + 1) * 768 + c * 256 + tid) * 8);
      }
      int bo = (kt & 1) * 6144;
      int ra0 = mt0 * 16 + l15 + kt, ra1 = mt1 * 16 + l15 + kt;
#pragma unroll
      for (int cb = 0; cb < 2; ++cb) {
        bf16x8 a0 = *(const bf16x8*)&s_c2[ra0 * 64 + ((((cb * 4 + quad) ^ ra0) & 7) << 3)];
        bf16x8 a1 = *(const bf16x8*)&s_c2[ra1 * 64 + ((((cb * 4 + quad) ^ ra1) & 7) << 3)];
#pragma unroll
        for (int nt = 0; nt < 6; ++nt) {
          int wr = nt * 16 + l15;
          bf16x8 bf = *(const bf16x8*)&s_w[bo + wr * 64 + ((((cb * 4 + quad) ^ wr) & 7) << 3)];
          acc[0][nt] = __builtin_amdgcn_mfma_f32_16x16x32_bf16(a0, bf, acc[0][nt], 0, 0, 0);
          acc[1][nt] = __builtin_amdgcn_mfma_f32_16x16x32_bf16(a1, bf, acc[1][nt], 0, 0, 0);
        }
      }
      if (kt < 7) {
        int bo2 = 6144 - bo;
#pragma unroll
        for (int c = 0; c < 3; ++c) {
          int ch = c * 256 + tid;
          int row = ch >> 3;
          *(bf16x8*)&s_w[bo2 + row * 64 + (((row ^ ch) & 7) << 3)] = w3t[c];
        }
      }
      __syncthreads();
    }
#pragma unroll
    for (int nt = 0; nt < 6; ++nt) {
      int co = nt * 16 + l15;
      float mx = 0.f;
#pragma unroll
      for (int mb = 0; mb < 2; ++mb) {
        int mt = mb ? mt1 : mt0;
#pragma unroll
        for (int r = 0; r < 4; ++r) {
          int l3 = t0 + mt * 16 + quad * 4 + r;
          if (l3 < 997) mx = fmaxf(mx, acc[mb][nt][r]);
        }
      }
      atomicMax(&s_max[co], __float_as_int(mx));
    }
  }
  __syncthreads();
  if (tid < 96) atomicMax((int*)&outmax[b * 224 + 128 + tid], s_max[tid]);
}

extern "C" void kernel_launch(void* const* d_in, const int* in_sizes, int n_in,
                              void* d_out, int out_size, void* d_ws, size_t ws_size,
                              hipStream_t stream) {
  (void)in_sizes; (void)n_in; (void)out_size; (void)ws_size;
  const float* x = (const float*)d_in[0];
  const int* ei = (const int*)d_in[1];
  const int* batch = (const int*)d_in[2];
  const int* seq = (const int*)d_in[3];
  const float* W1 = (const float*)d_in[4];
  // b1/b2/b3 (d_in[5,9,13]) dropped: constant channel bias cancels in BatchNorm
  const float* g1 = (const float*)d_in[6];
  const float* bt1 = (const float*)d_in[7];
  const float* W2 = (const float*)d_in[8];
  const float* g2 = (const float*)d_in[10];
  const float* bt2 = (const float*)d_in[11];
  const float* W3 = (const float*)d_in[12];
  const float* g3 = (const float*)d_in[14];
  const float* bt3 = (const float*)d_in[15];
  const float* emb = (const float*)d_in[16];
  const float* ck1 = (const float*)d_in[17];
  const float* cb1 = (const float*)d_in[18];
  const float* ck2 = (const float*)d_in[19];
  const float* cb2 = (const float*)d_in[20];
  const float* ck3 = (const float*)d_in[21];
  const float* cb3 = (const float*)d_in[22];
  const float* fw1 = (const float*)d_in[23];
  const float* fb1 = (const float*)d_in[24];
  const float* fw2 = (const float*)d_in[25];
  const float* fb2 = (const float*)d_in[26];
  const float* fw3 = (const float*)d_in[27];
  const float* fb3 = (const float*)d_in[28];
  const int* src = ei;
  const int* dst = ei + NE;

  float* ws = (float*)d_ws;
  float* bufA = ws;                 // 32768*128 (16 MB)
  float* bufB = ws + 4194304;       // 32768*128 (16 MB); head doubles as a5g (163840 f32)
  float* dis = ws + 8388608;        // 32768
  // contiguous zero region: stats(656) | cbuf(114688) | degi(32768 ints)
  float* stats = ws + 8421376;
  float* cbuf = ws + 8422032;
  int* degi = (int*)(ws + 8536720);
  int* base = degi + NN;                  // 32769
  int* cursor = base + NN + 1;
  unsigned short* csr_src = (unsigned short*)(cursor + NN);  // 131072 u16
  unsigned short* emb_bf = (unsigned short*)(ws + 8700564);  // (unused region kept for layout)
  unsigned short* wt1 = emb_bf + 3328;                       // (unused)
  unsigned short* wt2 = wt1 + 16384;                         // 12288
  unsigned short* wt3 = wt2 + 12288;                         // 49152
  float* e1 = ws + 8741140;                                  // 3328 f32 conv1 table (16B-aligned)
  float* a5g = bufB;                                         // L1 aggregate intermediate
  float* out = (float*)d_out;

  hipMemsetAsync(stats, 0, (656 + 114688 + 32768) * sizeof(float), stream);

  k_degprep<<<NE / 256, 256, 0, stream>>>(dst, degi, emb, ck1, ck2, ck3, wt2, wt3, e1);
  k_scan<<<1, 1024, 0, stream>>>(degi, base, cursor, dis);
  k_fill<<<NE / 256, 256, 0, stream>>>(src, dst, cursor, csr_src, NE);

  // ---- GNN layer 1: full-GPU aggregate + fc/stats
  k_agg5<<<NN / 64, 64, 0, stream>>>(x, dis, base, csr_src, a5g);
  k_fc5s<<<NN / 16, 256, 0, stream>>>(a5g, W1, bufA, stats);
  k_gbngather<64><<<NN * 16 / 256, 256, 0, stream>>>(bufA, dis, base, csr_src, stats, g1, bt1, bufB);
  k_fc4<128, 64, 4, false, false, true><<<1024, 256, 0, stream>>>(bufB, W2, nullptr, bufA, stats + 128, NN);

  // ---- merged: conv tiles (independent long pole) + gather128 (GNN layer-3 input)
  conv_mfma<<<8192, 256, 0, stream>>>(seq, e1, cb1, wt2, cb2, wt3, cb3,
                                      bufA, dis, base, csr_src, stats + 128, g2, bt2, bufB,
                                      cbuf);

  // ---- GNN layer-3 fc
  k_fc4<128, 128, 4, false, false, true><<<1024, 256, 0, stream>>>(bufB, W3, nullptr, bufA, stats + 384, NN);

  // ---- mean-pool (standalone) + fused regressor
  k_pool<<<NB, 128, 0, stream>>>(bufA, stats + 384, g3, bt3, batch, cbuf);
  k_reg<<<NB, 256, 0, stream>>>(cbuf, fw1, fb1, fw2, fb2, fw3, fb3, out);
}

// Round 10
// 407.989 us; speedup vs baseline: 1.1421x; 1.1421x over previous
//
#include <hip/hip_runtime.h>

#define NN 32768
#define NE 131072
#define NB 512
#define SL 1000

using bf16x8 = __attribute__((ext_vector_type(8))) short;
using f32x4  = __attribute__((ext_vector_type(4))) float;

static __device__ __forceinline__ unsigned short f2b(float f) {
  union { float f; unsigned u; } x; x.f = f;
  unsigned r = x.u + 0x7fffu + ((x.u >> 16) & 1u);  // RNE
  return (unsigned short)(r >> 16);
}

static __device__ __forceinline__ void bn_from_raw(float sum, float ssq, float g, float b,
                                                   float& sc, float& sh) {
  float m = sum / 32768.f;
  float v = ssq / 32768.f - m * m;
  sc = g * rsqrtf(v + 1e-5f);
  sh = b - m * sc;
}

// ---------------- fused degree + conv-weight prep + conv1 table ----------------
// E1[t][kt][co] = dot(emb[t][:], ck1[co][:][kt]) -- 26-vocab makes conv1 a table lookup.
// (emb_bf / wt1 jobs dropped: dead since the conv1-table rewrite.)
__global__ void k_degprep(const int* __restrict__ dst, int* __restrict__ degi,
                          const float* __restrict__ emb, const float* __restrict__ ck1,
                          const float* __restrict__ ck2, const float* __restrict__ ck3,
                          unsigned short* __restrict__ wt2, unsigned short* __restrict__ wt3,
                          float* __restrict__ e1) {
  int gid = blockIdx.x * 256 + threadIdx.x;
  atomicAdd(&degi[dst[gid]], 1);
  int idx = gid;
  if (idx < 12288) {
    int i = idx;
    int kt = i >> 11, co = (i >> 5) & 63, ci = i & 31;
    wt2[i] = f2b(ck2[co * 192 + ci * 6 + kt]);
  } else if (idx < 12288 + 49152) {
    int i = idx - 12288;
    int kt = i / 6144, co = (i >> 6) % 96, ci = i & 63;
    wt3[i] = f2b(ck3[co * 512 + ci * 8 + kt]);
  } else if (idx < 12288 + 49152 + 3328) {
    int i = idx - 61440;                     // i = t*128 + kt*32 + co
    int t = i >> 7, kt = (i >> 5) & 3, co = i & 31;
    const float* er = emb + t * 128;
    float s = 0.f;
#pragma unroll 4
    for (int ci = 0; ci < 128; ++ci) s += er[ci] * ck1[co * 512 + ci * 4 + kt];
    e1[i] = s;
  }
}

__global__ void k_scan(const int* __restrict__ degi, int* __restrict__ base,
                       int* __restrict__ cursor, float* __restrict__ dis) {
  __shared__ int part[1024];
  int tid = threadIdx.x;
  int v[32];
  int s = 0;
  int lo = tid * 32;
#pragma unroll
  for (int i = 0; i < 32; ++i) { v[i] = degi[lo + i]; s += v[i]; }
  part[tid] = s;
  __syncthreads();
  for (int off = 1; off < 1024; off <<= 1) {
    int val = (tid >= off) ? part[tid - off] : 0;
    __syncthreads();
    part[tid] += val;
    __syncthreads();
  }
  int run = (tid > 0) ? part[tid - 1] : 0;
#pragma unroll
  for (int i = 0; i < 32; ++i) {
    base[lo + i] = run;
    cursor[lo + i] = run;
    dis[lo + i] = rsqrtf(1.0f + (float)v[i]);
    run += v[i];
  }
  if (tid == 1023) base[NN] = run;
}

__global__ void k_fill(const int* __restrict__ src, const int* __restrict__ dst,
                       int* __restrict__ cursor, unsigned short* __restrict__ csr_src, int E) {
  int e = blockIdx.x * 256 + threadIdx.x;
  if (e < E) {
    int d = dst[e];
    int pos = atomicAdd(&cursor[d], 1);
    csr_src[pos] = (unsigned short)src[e];
  }
}

// ---------------- L1: aggregate(x,5ch) + 5->64 fc + fused stats ----------------
__launch_bounds__(256)
__global__ void k_gfc1s(const float* __restrict__ x, const float* __restrict__ dis,
                        const int* __restrict__ base, const unsigned short* __restrict__ csr_src,
                        const float* __restrict__ W1, float* __restrict__ out,
                        float* __restrict__ st) {
  __shared__ float sW[5][64];
  __shared__ float a5[256][6];
  __shared__ float red[16][64];
  int tid = threadIdx.x;
  for (int i = tid; i < 320; i += 256) sW[i >> 6][i & 63] = W1[i];
  int n = blockIdx.x * 256 + tid;
  float dn = dis[n];
  float s2 = dn * dn;
  const float* xn = x + (long)n * 5;
  float a0 = xn[0] * s2, a1 = xn[1] * s2, a2 = xn[2] * s2, a3 = xn[3] * s2, a4 = xn[4] * s2;
  int b0 = base[n], b1 = base[n + 1];
  int sNext = (b0 < b1) ? csr_src[b0] : 0;
  for (int j = b0; j < b1; ++j) {
    int s = sNext;
    if (j + 1 < b1) sNext = csr_src[j + 1];
    float coef = dis[s] * dn;
    const float* xs = x + (long)s * 5;
    a0 += xs[0] * coef; a1 += xs[1] * coef; a2 += xs[2] * coef;
    a3 += xs[3] * coef; a4 += xs[4] * coef;
  }
  a5[tid][0] = a0; a5[tid][1] = a1; a5[tid][2] = a2; a5[tid][3] = a3; a5[tid][4] = a4;
  __syncthreads();
  int co = (tid & 15) * 4, strip = tid >> 4;
  float4 s4 = {0.f, 0.f, 0.f, 0.f}, ss4 = {0.f, 0.f, 0.f, 0.f};
  for (int i = 0; i < 16; ++i) {
    int nl = strip * 16 + i;
    long nn = (long)blockIdx.x * 256 + nl;
    float4 acc = {0.f, 0.f, 0.f, 0.f};
#pragma unroll
    for (int ci = 0; ci < 5; ++ci) {
      float av = a5[nl][ci];
      acc.x += av * sW[ci][co];     acc.y += av * sW[ci][co + 1];
      acc.z += av * sW[ci][co + 2]; acc.w += av * sW[ci][co + 3];
    }
    *(float4*)&out[nn * 64 + co] = acc;
    s4.x += acc.x; s4.y += acc.y; s4.z += acc.z; s4.w += acc.w;
    ss4.x += acc.x * acc.x; ss4.y += acc.y * acc.y;
    ss4.z += acc.z * acc.z; ss4.w += acc.w * acc.w;
  }
  *(float4*)&red[strip][co] = s4;
  __syncthreads();
  if (tid < 64) {
    float t = 0.f;
#pragma unroll
    for (int s = 0; s < 16; ++s) t += red[s][tid];
    atomicAdd(&st[tid], t);
  }
  __syncthreads();
  *(float4*)&red[strip][co] = ss4;
  __syncthreads();
  if (tid < 64) {
    float t = 0.f;
#pragma unroll
    for (int s = 0; s < 16; ++s) t += red[s][tid];
    atomicAdd(&st[64 + tid], t);
  }
}

// ---------------- gather with BN-on-load (raw-sum stats), index prefetch ----------------
template<int C>
__launch_bounds__(256)
__global__ void k_gbngather(const float* __restrict__ in, const float* __restrict__ dis,
                            const int* __restrict__ base, const unsigned short* __restrict__ csr_src,
                            const float* __restrict__ st, const float* __restrict__ g,
                            const float* __restrict__ bt, float* __restrict__ out) {
  constexpr int TPN = C / 4;
  int t = blockIdx.x * 256 + threadIdx.x;
  int n = t / TPN;
  int c = (t % TPN) * 4;
  float4 sum4 = *(const float4*)&st[c];
  float4 ssq4 = *(const float4*)&st[C + c];
  float4 gg = *(const float4*)&g[c];
  float4 bb = *(const float4*)&bt[c];
  float4 sc4, sh4;
  bn_from_raw(sum4.x, ssq4.x, gg.x, bb.x, sc4.x, sh4.x);
  bn_from_raw(sum4.y, ssq4.y, gg.y, bb.y, sc4.y, sh4.y);
  bn_from_raw(sum4.z, ssq4.z, gg.z, bb.z, sc4.z, sh4.z);
  bn_from_raw(sum4.w, ssq4.w, gg.w, bb.w, sc4.w, sh4.w);
  float dn = dis[n];
  float s2 = dn * dn;
  float4 a = *(const float4*)&in[(long)n * C + c];
  float4 acc;
  acc.x = fmaxf(a.x * sc4.x + sh4.x, 0.f) * s2;
  acc.y = fmaxf(a.y * sc4.y + sh4.y, 0.f) * s2;
  acc.z = fmaxf(a.z * sc4.z + sh4.z, 0.f) * s2;
  acc.w = fmaxf(a.w * sc4.w + sh4.w, 0.f) * s2;
  int b0 = base[n], b1 = base[n + 1];
  int sNext = (b0 < b1) ? csr_src[b0] : 0;
  for (int j = b0; j < b1; ++j) {
    int s = sNext;
    if (j + 1 < b1) sNext = csr_src[j + 1];
    float coef = dis[s] * dn;
    float4 vv = *(const float4*)&in[(long)s * C + c];
    acc.x += fmaxf(vv.x * sc4.x + sh4.x, 0.f) * coef;
    acc.y += fmaxf(vv.y * sc4.y + sh4.y, 0.f) * coef;
    acc.z += fmaxf(vv.z * sc4.z + sh4.z, 0.f) * coef;
    acc.w += fmaxf(vv.w * sc4.w + sh4.w, 0.f) * coef;
  }
  *(float4*)&out[(long)n * C + c] = acc;
}

// ---------------- register-tiled dense layer with fused stats (GNN fc layers) ----------------
template<int C_OUT, int K, int TN, bool RELU, bool BIAS, bool STATS>
__launch_bounds__(256)
__global__ void k_fc4(const float* __restrict__ in, const float* __restrict__ W,
                      const float* __restrict__ bias, float* __restrict__ out,
                      float* __restrict__ st, int N) {
  constexpr int CO4 = C_OUT / 4;
  constexpr int GPB = 256 / CO4;
  int g = blockIdx.x * GPB + threadIdx.x / CO4;
  long n0 = (long)g * TN;
  if (!STATS && n0 >= N) return;
  int co = (threadIdx.x % CO4) * 4;
  float4 acc[TN];
  float4 b4 = {0.f, 0.f, 0.f, 0.f};
  if (BIAS) b4 = *(const float4*)&bias[co];
#pragma unroll
  for (int t = 0; t < TN; ++t) acc[t] = b4;
  for (int ci = 0; ci < K; ci += 4) {
    float4 w0 = *(const float4*)&W[(long)(ci + 0) * C_OUT + co];
    float4 w1 = *(const float4*)&W[(long)(ci + 1) * C_OUT + co];
    float4 w2 = *(const float4*)&W[(long)(ci + 2) * C_OUT + co];
    float4 w3 = *(const float4*)&W[(long)(ci + 3) * C_OUT + co];
#pragma unroll
    for (int t = 0; t < TN; ++t) {
      float4 a = *(const float4*)&in[(n0 + t) * K + ci];
      acc[t].x += a.x * w0.x; acc[t].y += a.x * w0.y; acc[t].z += a.x * w0.z; acc[t].w += a.x * w0.w;
      acc[t].x += a.y * w1.x; acc[t].y += a.y * w1.y; acc[t].z += a.y * w1.z; acc[t].w += a.y * w1.w;
      acc[t].x += a.z * w2.x; acc[t].y += a.z * w2.y; acc[t].z += a.z * w2.z; acc[t].w += a.z * w2.w;
      acc[t].x += a.w * w3.x; acc[t].y += a.w * w3.y; acc[t].z += a.w * w3.z; acc[t].w += a.w * w3.w;
    }
  }
  float4 s4 = {0.f, 0.f, 0.f, 0.f}, ss4 = {0.f, 0.f, 0.f, 0.f};
#pragma unroll
  for (int t = 0; t < TN; ++t) {
    float4 o = acc[t];
    if (RELU) {
      o.x = fmaxf(o.x, 0.f); o.y = fmaxf(o.y, 0.f);
      o.z = fmaxf(o.z, 0.f); o.w = fmaxf(o.w, 0.f);
    }
    *(float4*)&out[(n0 + t) * C_OUT + co] = o;
    if (STATS) {
      s4.x += o.x; s4.y += o.y; s4.z += o.z; s4.w += o.w;
      ss4.x += o.x * o.x; ss4.y += o.y * o.y;
      ss4.z += o.z * o.z; ss4.w += o.w * o.w;
    }
  }
  if (STATS) {
    __shared__ float red2[GPB][C_OUT];
    int grp = threadIdx.x / CO4;
    *(float4*)&red2[grp][co] = s4;
    __syncthreads();
    if (threadIdx.x < C_OUT) {
      float t = 0.f;
#pragma unroll
      for (int s = 0; s < GPB; ++s) t += red2[s][threadIdx.x];
      atomicAdd(&st[threadIdx.x], t);
    }
    __syncthreads();
    *(float4*)&red2[grp][co] = ss4;
    __syncthreads();
    if (threadIdx.x < C_OUT) {
      float t = 0.f;
#pragma unroll
      for (int s = 0; s < GPB; ++s) t += red2[s][threadIdx.x];
      atomicAdd(&st[C_OUT + threadIdx.x], t);
    }
  }
}

// ---------------- fused regressor: per-sample 224 -> 512 -> 256 -> 1 ----------------
__launch_bounds__(256)
__global__ void k_reg(const float* __restrict__ cbuf,
                      const float* __restrict__ fw1, const float* __restrict__ fb1,
                      const float* __restrict__ fw2, const float* __restrict__ fb2,
                      const float* __restrict__ fw3, const float* __restrict__ fb3,
                      float* __restrict__ out) {
  __shared__ float cin[224];
  __shared__ float h1[512];
  __shared__ float h2[256];
  __shared__ float red[4];
  int b = blockIdx.x, t = threadIdx.x;
  if (t < 224) cin[t] = cbuf[b * 224 + t];
  __syncthreads();
  {
    float a0 = fb1[t], a1 = fb1[t + 256];
    for (int ci = 0; ci < 224; ++ci) {
      float av = cin[ci];
      a0 += av * fw1[ci * 512 + t];
      a1 += av * fw1[ci * 512 + t + 256];
    }
    h1[t] = fmaxf(a0, 0.f);
    h1[t + 256] = fmaxf(a1, 0.f);
  }
  __syncthreads();
  {
    float a = fb2[t];
    for (int ci = 0; ci < 512; ++ci) a += h1[ci] * fw2[ci * 256 + t];
    h2[t] = fmaxf(a, 0.f);
  }
  __syncthreads();
  {
    float p = h2[t] * fw3[t];
#pragma unroll
    for (int off = 32; off > 0; off >>= 1) p += __shfl_down(p, off, 64);
    if ((t & 63) == 0) red[t >> 6] = p;
    __syncthreads();
    if (t == 0) out[b] = red[0] + red[1] + red[2] + red[3] + fb3[0];
  }
}

// ---------------- protein encoder: table-conv1 + bf16 MFMA conv2/conv3 (R5, best measured) ----
// 128-position tiles, 256 thr, LDS 53760, 3 blocks/CU; pool block (x==8) hides the GNN
// mean-pool inside this grid -- the only placement that measured net-positive (R8/R9
// alternatives exposed it). Conv must therefore run after fc4 layer-3.
__launch_bounds__(256, 3)
__global__ void conv_mfma(const int* __restrict__ seq, const float* __restrict__ e1g,
                          const float* __restrict__ cb1,
                          const unsigned short* __restrict__ wt2g, const float* __restrict__ cb2,
                          const unsigned short* __restrict__ wt3g, const float* __restrict__ cb3,
                          const float* __restrict__ agg, const float* __restrict__ st3,
                          const float* __restrict__ g3, const float* __restrict__ bt3,
                          const int* __restrict__ batch, float* __restrict__ outmax) {
  __shared__ __align__(16) unsigned short s_w[12288];
  __shared__ __align__(16) unsigned short s_c1[4864];   // 152 rows x 32 (XOR 16B-slot swizzle, key row&3)
  __shared__ __align__(16) unsigned short s_c2[9216];   // 144 rows x 64 (XOR 16B-slot swizzle, key row&7)
  __shared__ int s_tok[152];
  __shared__ int s_max[96];

  int tid = threadIdx.x;
  int b = blockIdx.y;

  if (blockIdx.x == 8) {  // ---- pooling block (GNN mean-pool, runs concurrent with conv tiles)
    __shared__ int s_lo, s_hi;
    if (tid == 0) {
      int lo = 0, hi = NN;
      while (lo < hi) { int m = (lo + hi) >> 1; if (batch[m] < b) lo = m + 1; else hi = m; }
      s_lo = lo;
      hi = NN;
      while (lo < hi) { int m = (lo + hi) >> 1; if (batch[m] <= b) lo = m + 1; else hi = m; }
      s_hi = lo;
    }
    __syncthreads();
    if (tid < 128) {
      int lo = s_lo, hi = s_hi, c = tid;
      float sc, sh;
      bn_from_raw(st3[c], st3[128 + c], g3[c], bt3[c], sc, sh);
      float s = 0.f;
      for (int n = lo; n < hi; ++n) s += fmaxf(agg[(long)n * 128 + c] * sc + sh, 0.f);
      outmax[b * 224 + c] = s / fmaxf((float)(hi - lo), 1.0f);
    }
    return;
  }

  int t0 = blockIdx.x * 128;

  if (tid < 96) s_max[tid] = 0;
  if (tid < 152) {
    int p = t0 - 6 + tid;
    s_tok[tid] = (p >= 0 && p < SL) ? seq[b * SL + p] : 0;
  }
  // zero s_c1 rows 144..151 (read-ahead region of conv2's 9th tile)
  if (tid < 128) ((int*)(s_c1 + 144 * 32))[tid] = 0;

  // phase 0: stage conv2 weights (full 384 rows x 32) -- s_w has no other user now
  {
#pragma unroll
    for (int c = 0; c < 6; ++c) {
      int ch = c * 256 + tid;
      int row = ch >> 2;
      *(bf16x8*)&s_w[row * 32 + (((row ^ ch) & 3) << 3)] = *(const bf16x8*)(wt2g + ch * 8);
    }
  }
  __syncthreads();  // barrier 1: s_tok + s_w(conv2) + c1 tail zeros ready

  int lane = tid & 63, wave = tid >> 6;
  int l15 = lane & 15, quad = lane >> 4;

  // ---- conv1 via table: rows 0..143, 32 ch each; 2 threads per row (16 ch per thread)
  {
    bool edge = (blockIdx.x == 0) || (blockIdx.x == 7);
#pragma unroll
    for (int pass = 0; pass < 2; ++pass) {
      int m = (pass == 0) ? (tid >> 1) : (128 + (tid >> 1));
      bool act = (pass == 0) || (tid < 32);
      if (act) {
        int co0 = (tid & 1) * 16;
        f32x4 a4[4];
#pragma unroll
        for (int q = 0; q < 4; ++q) a4[q] = *(const f32x4*)&cb1[co0 + q * 4];
#pragma unroll
        for (int kt = 0; kt < 4; ++kt) {
          const float* e = e1g + s_tok[m + kt] * 128 + kt * 32 + co0;
#pragma unroll
          for (int q = 0; q < 4; ++q) {
            f32x4 v = *(const f32x4*)&e[q * 4];
            a4[q][0] += v[0]; a4[q][1] += v[1]; a4[q][2] += v[2]; a4[q][3] += v[3];
          }
        }
        int l1 = t0 - 5 + m;
        bool ok = !edge || (l1 >= 0 && l1 < 999);   // uniform per thread (m fixed)
#pragma unroll
        for (int q = 0; q < 4; ++q) {
#pragma unroll
          for (int e2 = 0; e2 < 4; e2 += 2) {
            int co = co0 + q * 4 + e2;
            unsigned lo = ok ? (unsigned)f2b(fmaxf(a4[q][e2], 0.f)) : 0u;
            unsigned hi = ok ? (unsigned)f2b(fmaxf(a4[q][e2 + 1], 0.f)) : 0u;
            *(unsigned*)&s_c1[m * 32 + ((((co >> 3) ^ m) & 3) << 3) + (co & 7)] = lo | (hi << 16);
          }
        }
      }
    }
  }
  __syncthreads();  // barrier 2: s_c1 ready

  // ---- conv2: A from s_c1, B from s_w (staged phase 0)
  {
    int mt0 = wave, mt1 = wave + 4;
    f32x4 acc[2][4];
#pragma unroll
    for (int nt = 0; nt < 4; ++nt) {
      float bv = cb2[nt * 16 + l15];
      acc[0][nt] = (f32x4){bv, bv, bv, bv};
      acc[1][nt] = (f32x4){bv, bv, bv, bv};
    }
    for (int kt = 0; kt < 6; ++kt) {
      int r0 = mt0 * 16 + l15 + kt, r1 = mt1 * 16 + l15 + kt;
      bf16x8 a0 = *(const bf16x8*)&s_c1[r0 * 32 + (((quad ^ r0) & 3) << 3)];
      bf16x8 a1 = *(const bf16x8*)&s_c1[r1 * 32 + (((quad ^ r1) & 3) << 3)];
#pragma unroll
      for (int nt = 0; nt < 4; ++nt) {
        int wr = kt * 64 + nt * 16 + l15;
        bf16x8 bf = *(const bf16x8*)&s_w[wr * 32 + (((quad ^ wr) & 3) << 3)];
        acc[0][nt] = __builtin_amdgcn_mfma_f32_16x16x32_bf16(a0, bf, acc[0][nt], 0, 0, 0);
        acc[1][nt] = __builtin_amdgcn_mfma_f32_16x16x32_bf16(a1, bf, acc[1][nt], 0, 0, 0);
      }
    }
#pragma unroll
    for (int mb = 0; mb < 2; ++mb) {
      int mt = mb ? mt1 : mt0;
#pragma unroll
      for (int nt = 0; nt < 4; ++nt) {
        int co = nt * 16 + l15;
#pragma unroll
        for (int r = 0; r < 4; ++r) {
          int m = mt * 16 + quad * 4 + r;
          int l2 = t0 - 3 + m;
          unsigned short hv = f2b(fmaxf(acc[mb][nt][r], 0.f));
          s_c2[m * 64 + ((((co >> 3) ^ m) & 7) << 3) + (co & 7)] = (l2 >= 0 && l2 < 998) ? hv : (unsigned short)0;
        }
      }
    }
    if (wave == 0) {
      f32x4 acc8[4];
#pragma unroll
      for (int nt = 0; nt < 4; ++nt) {
        float bv = cb2[nt * 16 + l15];
        acc8[nt] = (f32x4){bv, bv, bv, bv};
      }
      for (int kt = 0; kt < 6; ++kt) {
        int r0 = 128 + l15 + kt;
        bf16x8 a0 = *(const bf16x8*)&s_c1[r0 * 32 + (((quad ^ r0) & 3) << 3)];
#pragma unroll
        for (int nt = 0; nt < 4; ++nt) {
          int wr = kt * 64 + nt * 16 + l15;
          bf16x8 bf = *(const bf16x8*)&s_w[wr * 32 + (((quad ^ wr) & 3) << 3)];
          acc8[nt] = __builtin_amdgcn_mfma_f32_16x16x32_bf16(a0, bf, acc8[nt], 0, 0, 0);
        }
      }
#pragma unroll
      for (int nt = 0; nt < 4; ++nt) {
        int co = nt * 16 + l15;
#pragma unroll
        for (int r = 0; r < 4; ++r) {
          int m = 128 + quad * 4 + r;
          int l2 = t0 - 3 + m;
          unsigned short hv = f2b(fmaxf(acc8[nt][r], 0.f));
          s_c2[m * 64 + ((((co >> 3) ^ m) & 7) << 3) + (co & 7)] = (l2 >= 0 && l2 < 998) ? hv : (unsigned short)0;
        }
      }
    }
  }

  // ---- stage conv3 kt=0 weights (dbuf 2 x [96][64])
  {
    bf16x8 w3t[3];
#pragma unroll
    for (int c = 0; c < 3; ++c) w3t[c] = *(const bf16x8*)(wt3g + (c * 256 + tid) * 8);
    __syncthreads();  // conv2 compute read s_w/s_c2 with no trailing barrier
#pragma unroll
    for (int c = 0; c < 3; ++c) {
      int ch = c * 256 + tid;
      int row = ch >> 3;
      *(bf16x8*)&s_w[row * 64 + (((row ^ ch) & 7) << 3)] = w3t[c];
    }
    __syncthreads();
  }

  // ---- conv3: kt double-buffered weights + fused max-pool
  {
    int mt0 = wave, mt1 = wave + 4;
    f32x4 acc[2][6];
#pragma unroll
    for (int nt = 0; nt < 6; ++nt) {
      float bv = cb3[nt * 16 + l15];
      acc[0][nt] = (f32x4){bv, bv, bv, bv};
      acc[1][nt] = (f32x4){bv, bv, bv, bv};
    }
    for (int kt = 0; kt < 8; ++kt) {
      bf16x8 w3t[3];
      if (kt < 7) {
#pragma unroll
        for (int c = 0; c < 3; ++c)
          w3t[c] = *(const bf16x8*)(wt3g + ((kt + 1) * 768 + c * 256 + tid) * 8);
      }
      int bo = (kt & 1) * 6144;
      int ra0 = mt0 * 16 + l15 + kt, ra1 = mt1 * 16 + l15 + kt;
#pragma unroll
      for (int cb = 0; cb < 2; ++cb) {
        bf16x8 a0 = *(const bf16x8*)&s_c2[ra0 * 64 + ((((cb * 4 + quad) ^ ra0) & 7) << 3)];
        bf16x8 a1 = *(const bf16x8*)&s_c2[ra1 * 64 + ((((cb * 4 + quad) ^ ra1) & 7) << 3)];
#pragma unroll
        for (int nt = 0; nt < 6; ++nt) {
          int wr = nt * 16 + l15;
          bf16x8 bf = *(const bf16x8*)&s_w[bo + wr * 64 + ((((cb * 4 + quad) ^ wr) & 7) << 3)];
          acc[0][nt] = __builtin_amdgcn_mfma_f32_16x16x32_bf16(a0, bf, acc[0][nt], 0, 0, 0);
          acc[1][nt] = __builtin_amdgcn_mfma_f32_16x16x32_bf16(a1, bf, acc[1][nt], 0, 0, 0);
        }
      }
      if (kt < 7) {
        int bo2 = 6144 - bo;
#pragma unroll
        for (int c = 0; c < 3; ++c) {
          int ch = c * 256 + tid;
          int row = ch >> 3;
          *(bf16x8*)&s_w[bo2 + row * 64 + (((row ^ ch) & 7) << 3)] = w3t[c];
        }
      }
      __syncthreads();
    }
#pragma unroll
    for (int nt = 0; nt < 6; ++nt) {
      int co = nt * 16 + l15;
      float mx = 0.f;
#pragma unroll
      for (int mb = 0; mb < 2; ++mb) {
        int mt = mb ? mt1 : mt0;
#pragma unroll
        for (int r = 0; r < 4; ++r) {
          int l3 = t0 + mt * 16 + quad * 4 + r;
          if (l3 < 997) mx = fmaxf(mx, acc[mb][nt][r]);
        }
      }
      atomicMax(&s_max[co], __float_as_int(mx));
    }
  }
  __syncthreads();
  if (tid < 96) atomicMax((int*)&outmax[b * 224 + 128 + tid], s_max[tid]);
}

extern "C" void kernel_launch(void* const* d_in, const int* in_sizes, int n_in,
                              void* d_out, int out_size, void* d_ws, size_t ws_size,
                              hipStream_t stream) {
  (void)in_sizes; (void)n_in; (void)out_size; (void)ws_size;
  const float* x = (const float*)d_in[0];
  const int* ei = (const int*)d_in[1];
  const int* batch = (const int*)d_in[2];
  const int* seq = (const int*)d_in[3];
  const float* W1 = (const float*)d_in[4];
  // b1/b2/b3 (d_in[5,9,13]) dropped: constant channel bias cancels in BatchNorm
  const float* g1 = (const float*)d_in[6];
  const float* bt1 = (const float*)d_in[7];
  const float* W2 = (const float*)d_in[8];
  const float* g2 = (const float*)d_in[10];
  const float* bt2 = (const float*)d_in[11];
  const float* W3 = (const float*)d_in[12];
  const float* g3 = (const float*)d_in[14];
  const float* bt3 = (const float*)d_in[15];
  const float* emb = (const float*)d_in[16];
  const float* ck1 = (const float*)d_in[17];
  const float* cb1 = (const float*)d_in[18];
  const float* ck2 = (const float*)d_in[19];
  const float* cb2 = (const float*)d_in[20];
  const float* ck3 = (const float*)d_in[21];
  const float* cb3 = (const float*)d_in[22];
  const float* fw1 = (const float*)d_in[23];
  const float* fb1 = (const float*)d_in[24];
  const float* fw2 = (const float*)d_in[25];
  const float* fb2 = (const float*)d_in[26];
  const float* fw3 = (const float*)d_in[27];
  const float* fb3 = (const float*)d_in[28];
  const int* src = ei;
  const int* dst = ei + NE;

  float* ws = (float*)d_ws;
  float* bufA = ws;                 // 32768*128 (16 MB)
  float* bufB = ws + 4194304;       // 32768*128 (16 MB)
  float* dis = ws + 8388608;        // 32768
  // contiguous zero region: stats(656) | cbuf(114688) | degi(32768 ints)
  float* stats = ws + 8421376;
  float* cbuf = ws + 8422032;
  int* degi = (int*)(ws + 8536720);
  int* base = degi + NN;                  // 32769
  int* cursor = base + NN + 1;
  unsigned short* csr_src = (unsigned short*)(cursor + NN);  // 131072 u16
  unsigned short* emb_bf = (unsigned short*)(ws + 8700564);  // (unused region kept for layout)
  unsigned short* wt1 = emb_bf + 3328;                       // (unused)
  unsigned short* wt2 = wt1 + 16384;                         // 12288
  unsigned short* wt3 = wt2 + 12288;                         // 49152
  float* e1 = ws + 8741140;                                  // 3328 f32 conv1 table (16B-aligned)
  float* out = (float*)d_out;

  hipMemsetAsync(stats, 0, (656 + 114688 + 32768) * sizeof(float), stream);

  k_degprep<<<NE / 256, 256, 0, stream>>>(dst, degi, emb, ck1, ck2, ck3, wt2, wt3, e1);
  k_scan<<<1, 1024, 0, stream>>>(degi, base, cursor, dis);
  k_fill<<<NE / 256, 256, 0, stream>>>(src, dst, cursor, csr_src, NE);

  // ---- GNN: 5 fused fat-grid kernels (pool fused into conv grid)
  k_gfc1s<<<NN / 256, 256, 0, stream>>>(x, dis, base, csr_src, W1, bufA, stats);
  k_gbngather<64><<<NN * 16 / 256, 256, 0, stream>>>(bufA, dis, base, csr_src, stats, g1, bt1, bufB);
  k_fc4<128, 64, 4, false, false, true><<<1024, 256, 0, stream>>>(bufB, W2, nullptr, bufA, stats + 128, NN);
  k_gbngather<128><<<NN * 32 / 256, 256, 0, stream>>>(bufA, dis, base, csr_src, stats + 128, g2, bt2, bufB);
  k_fc4<128, 128, 4, false, false, true><<<1024, 256, 0, stream>>>(bufB, W3, nullptr, bufA, stats + 384, NN);

  // ---- protein encoder + fused BN3/pool -> cbuf
  conv_mfma<<<dim3(9, NB), 256, 0, stream>>>(seq, e1, cb1, wt2, cb2, wt3, cb3,
                                             bufA, stats + 384, g3, bt3, batch, cbuf);

  // ---- fused regressor (one block per sample)
  k_reg<<<NB, 256, 0, stream>>>(cbuf, fw1, fb1, fw2, fb2, fw3, fb3, out);
}

// Round 11
// 406.621 us; speedup vs baseline: 1.1459x; 1.0034x over previous
//
#include <hip/hip_runtime.h>

#define NN 32768
#define NE 131072
#define NB 512
#define SL 1000

using bf16x8 = __attribute__((ext_vector_type(8))) short;
using f32x4  = __attribute__((ext_vector_type(4))) float;

static __device__ __forceinline__ unsigned short f2b(float f) {
  union { float f; unsigned u; } x; x.f = f;
  unsigned r = x.u + 0x7fffu + ((x.u >> 16) & 1u);  // RNE
  return (unsigned short)(r >> 16);
}

static __device__ __forceinline__ void bn_from_raw(float sum, float ssq, float g, float b,
                                                   float& sc, float& sh) {
  float m = sum / 32768.f;
  float v = ssq / 32768.f - m * m;
  sc = g * rsqrtf(v + 1e-5f);
  sh = b - m * sc;
}

// ---------------- fused degree + conv-weight prep + conv1 table ----------------
__global__ void k_degprep(const int* __restrict__ dst, int* __restrict__ degi,
                          const float* __restrict__ emb, const float* __restrict__ ck1,
                          const float* __restrict__ ck2, const float* __restrict__ ck3,
                          unsigned short* __restrict__ wt2, unsigned short* __restrict__ wt3,
                          float* __restrict__ e1) {
  int gid = blockIdx.x * 256 + threadIdx.x;
  atomicAdd(&degi[dst[gid]], 1);
  int idx = gid;
  if (idx < 12288) {
    int i = idx;
    int kt = i >> 11, co = (i >> 5) & 63, ci = i & 31;
    wt2[i] = f2b(ck2[co * 192 + ci * 6 + kt]);
  } else if (idx < 12288 + 49152) {
    int i = idx - 12288;
    int kt = i / 6144, co = (i >> 6) % 96, ci = i & 63;
    wt3[i] = f2b(ck3[co * 512 + ci * 8 + kt]);
  } else if (idx < 12288 + 49152 + 3328) {
    int i = idx - 61440;                     // i = t*128 + kt*32 + co
    int t = i >> 7, kt = (i >> 5) & 3, co = i & 31;
    const float* er = emb + t * 128;
    float s = 0.f;
#pragma unroll 4
    for (int ci = 0; ci < 128; ++ci) s += er[ci] * ck1[co * 512 + ci * 4 + kt];
    e1[i] = s;
  }
}

__global__ void k_scan(const int* __restrict__ degi, int* __restrict__ base,
                       int* __restrict__ cursor, float* __restrict__ dis) {
  __shared__ int part[1024];
  int tid = threadIdx.x;
  int v[32];
  int s = 0;
  int lo = tid * 32;
#pragma unroll
  for (int i = 0; i < 32; ++i) { v[i] = degi[lo + i]; s += v[i]; }
  part[tid] = s;
  __syncthreads();
  for (int off = 1; off < 1024; off <<= 1) {
    int val = (tid >= off) ? part[tid - off] : 0;
    __syncthreads();
    part[tid] += val;
    __syncthreads();
  }
  int run = (tid > 0) ? part[tid - 1] : 0;
#pragma unroll
  for (int i = 0; i < 32; ++i) {
    base[lo + i] = run;
    cursor[lo + i] = run;
    dis[lo + i] = rsqrtf(1.0f + (float)v[i]);
    run += v[i];
  }
  if (tid == 1023) base[NN] = run;
}

__global__ void k_fill(const int* __restrict__ src, const int* __restrict__ dst,
                       int* __restrict__ cursor, unsigned short* __restrict__ csr_src, int E) {
  int e = blockIdx.x * 256 + threadIdx.x;
  if (e < E) {
    int d = dst[e];
    int pos = atomicAdd(&cursor[d], 1);
    csr_src[pos] = (unsigned short)src[e];
  }
}

// ---------------- L1: aggregate(x,5ch) + 5->64 fc + fused stats ----------------
__launch_bounds__(256)
__global__ void k_gfc1s(const float* __restrict__ x, const float* __restrict__ dis,
                        const int* __restrict__ base, const unsigned short* __restrict__ csr_src,
                        const float* __restrict__ W1, float* __restrict__ out,
                        float* __restrict__ st) {
  __shared__ float sW[5][64];
  __shared__ float a5[256][6];
  __shared__ float red[16][64];
  int tid = threadIdx.x;
  for (int i = tid; i < 320; i += 256) sW[i >> 6][i & 63] = W1[i];
  int n = blockIdx.x * 256 + tid;
  float dn = dis[n];
  float s2 = dn * dn;
  const float* xn = x + (long)n * 5;
  float a0 = xn[0] * s2, a1 = xn[1] * s2, a2 = xn[2] * s2, a3 = xn[3] * s2, a4 = xn[4] * s2;
  int b0 = base[n], b1 = base[n + 1];
  int sNext = (b0 < b1) ? csr_src[b0] : 0;
  for (int j = b0; j < b1; ++j) {
    int s = sNext;
    if (j + 1 < b1) sNext = csr_src[j + 1];
    float coef = dis[s] * dn;
    const float* xs = x + (long)s * 5;
    a0 += xs[0] * coef; a1 += xs[1] * coef; a2 += xs[2] * coef;
    a3 += xs[3] * coef; a4 += xs[4] * coef;
  }
  a5[tid][0] = a0; a5[tid][1] = a1; a5[tid][2] = a2; a5[tid][3] = a3; a5[tid][4] = a4;
  __syncthreads();
  int co = (tid & 15) * 4, strip = tid >> 4;
  float4 s4 = {0.f, 0.f, 0.f, 0.f}, ss4 = {0.f, 0.f, 0.f, 0.f};
  for (int i = 0; i < 16; ++i) {
    int nl = strip * 16 + i;
    long nn = (long)blockIdx.x * 256 + nl;
    float4 acc = {0.f, 0.f, 0.f, 0.f};
#pragma unroll
    for (int ci = 0; ci < 5; ++ci) {
      float av = a5[nl][ci];
      acc.x += av * sW[ci][co];     acc.y += av * sW[ci][co + 1];
      acc.z += av * sW[ci][co + 2]; acc.w += av * sW[ci][co + 3];
    }
    *(float4*)&out[nn * 64 + co] = acc;
    s4.x += acc.x; s4.y += acc.y; s4.z += acc.z; s4.w += acc.w;
    ss4.x += acc.x * acc.x; ss4.y += acc.y * acc.y;
    ss4.z += acc.z * acc.z; ss4.w += acc.w * acc.w;
  }
  *(float4*)&red[strip][co] = s4;
  __syncthreads();
  if (tid < 64) {
    float t = 0.f;
#pragma unroll
    for (int s = 0; s < 16; ++s) t += red[s][tid];
    atomicAdd(&st[tid], t);
  }
  __syncthreads();
  *(float4*)&red[strip][co] = ss4;
  __syncthreads();
  if (tid < 64) {
    float t = 0.f;
#pragma unroll
    for (int s = 0; s < 16; ++s) t += red[s][tid];
    atomicAdd(&st[64 + tid], t);
  }
}

// ---------------- gather with BN-on-load (raw-sum stats), index prefetch ----------------
template<int C>
__launch_bounds__(256)
__global__ void k_gbngather(const float* __restrict__ in, const float* __restrict__ dis,
                            const int* __restrict__ base, const unsigned short* __restrict__ csr_src,
                            const float* __restrict__ st, const float* __restrict__ g,
                            const float* __restrict__ bt, float* __restrict__ out) {
  constexpr int TPN = C / 4;
  int t = blockIdx.x * 256 + threadIdx.x;
  int n = t / TPN;
  int c = (t % TPN) * 4;
  float4 sum4 = *(const float4*)&st[c];
  float4 ssq4 = *(const float4*)&st[C + c];
  float4 gg = *(const float4*)&g[c];
  float4 bb = *(const float4*)&bt[c];
  float4 sc4, sh4;
  bn_from_raw(sum4.x, ssq4.x, gg.x, bb.x, sc4.x, sh4.x);
  bn_from_raw(sum4.y, ssq4.y, gg.y, bb.y, sc4.y, sh4.y);
  bn_from_raw(sum4.z, ssq4.z, gg.z, bb.z, sc4.z, sh4.z);
  bn_from_raw(sum4.w, ssq4.w, gg.w, bb.w, sc4.w, sh4.w);
  float dn = dis[n];
  float s2 = dn * dn;
  float4 a = *(const float4*)&in[(long)n * C + c];
  float4 acc;
  acc.x = fmaxf(a.x * sc4.x + sh4.x, 0.f) * s2;
  acc.y = fmaxf(a.y * sc4.y + sh4.y, 0.f) * s2;
  acc.z = fmaxf(a.z * sc4.z + sh4.z, 0.f) * s2;
  acc.w = fmaxf(a.w * sc4.w + sh4.w, 0.f) * s2;
  int b0 = base[n], b1 = base[n + 1];
  int sNext = (b0 < b1) ? csr_src[b0] : 0;
  for (int j = b0; j < b1; ++j) {
    int s = sNext;
    if (j + 1 < b1) sNext = csr_src[j + 1];
    float coef = dis[s] * dn;
    float4 vv = *(const float4*)&in[(long)s * C + c];
    acc.x += fmaxf(vv.x * sc4.x + sh4.x, 0.f) * coef;
    acc.y += fmaxf(vv.y * sc4.y + sh4.y, 0.f) * coef;
    acc.z += fmaxf(vv.z * sc4.z + sh4.z, 0.f) * coef;
    acc.w += fmaxf(vv.w * sc4.w + sh4.w, 0.f) * coef;
  }
  *(float4*)&out[(long)n * C + c] = acc;
}

// ---------------- register-tiled dense layer with fused stats (GNN fc layers) ----------------
template<int C_OUT, int K, int TN, bool RELU, bool BIAS, bool STATS>
__launch_bounds__(256)
__global__ void k_fc4(const float* __restrict__ in, const float* __restrict__ W,
                      const float* __restrict__ bias, float* __restrict__ out,
                      float* __restrict__ st, int N) {
  constexpr int CO4 = C_OUT / 4;
  constexpr int GPB = 256 / CO4;
  int g = blockIdx.x * GPB + threadIdx.x / CO4;
  long n0 = (long)g * TN;
  if (!STATS && n0 >= N) return;
  int co = (threadIdx.x % CO4) * 4;
  float4 acc[TN];
  float4 b4 = {0.f, 0.f, 0.f, 0.f};
  if (BIAS) b4 = *(const float4*)&bias[co];
#pragma unroll
  for (int t = 0; t < TN; ++t) acc[t] = b4;
  for (int ci = 0; ci < K; ci += 4) {
    float4 w0 = *(const float4*)&W[(long)(ci + 0) * C_OUT + co];
    float4 w1 = *(const float4*)&W[(long)(ci + 1) * C_OUT + co];
    float4 w2 = *(const float4*)&W[(long)(ci + 2) * C_OUT + co];
    float4 w3 = *(const float4*)&W[(long)(ci + 3) * C_OUT + co];
#pragma unroll
    for (int t = 0; t < TN; ++t) {
      float4 a = *(const float4*)&in[(n0 + t) * K + ci];
      acc[t].x += a.x * w0.x; acc[t].y += a.x * w0.y; acc[t].z += a.x * w0.z; acc[t].w += a.x * w0.w;
      acc[t].x += a.y * w1.x; acc[t].y += a.y * w1.y; acc[t].z += a.y * w1.z; acc[t].w += a.y * w1.w;
      acc[t].x += a.z * w2.x; acc[t].y += a.z * w2.y; acc[t].z += a.z * w2.z; acc[t].w += a.z * w2.w;
      acc[t].x += a.w * w3.x; acc[t].y += a.w * w3.y; acc[t].z += a.w * w3.z; acc[t].w += a.w * w3.w;
    }
  }
  float4 s4 = {0.f, 0.f, 0.f, 0.f}, ss4 = {0.f, 0.f, 0.f, 0.f};
#pragma unroll
  for (int t = 0; t < TN; ++t) {
    float4 o = acc[t];
    if (RELU) {
      o.x = fmaxf(o.x, 0.f); o.y = fmaxf(o.y, 0.f);
      o.z = fmaxf(o.z, 0.f); o.w = fmaxf(o.w, 0.f);
    }
    *(float4*)&out[(n0 + t) * C_OUT + co] = o;
    if (STATS) {
      s4.x += o.x; s4.y += o.y; s4.z += o.z; s4.w += o.w;
      ss4.x += o.x * o.x; ss4.y += o.y * o.y;
      ss4.z += o.z * o.z; ss4.w += o.w * o.w;
    }
  }
  if (STATS) {
    __shared__ float red2[GPB][C_OUT];
    int grp = threadIdx.x / CO4;
    *(float4*)&red2[grp][co] = s4;
    __syncthreads();
    if (threadIdx.x < C_OUT) {
      float t = 0.f;
#pragma unroll
      for (int s = 0; s < GPB; ++s) t += red2[s][threadIdx.x];
      atomicAdd(&st[threadIdx.x], t);
    }
    __syncthreads();
    *(float4*)&red2[grp][co] = ss4;
    __syncthreads();
    if (threadIdx.x < C_OUT) {
      float t = 0.f;
#pragma unroll
      for (int s = 0; s < GPB; ++s) t += red2[s][threadIdx.x];
      atomicAdd(&st[C_OUT + threadIdx.x], t);
    }
  }
}

// ---------------- GNN mean-pool, node-dim split 4x (2048 blocks -> 8 blocks/CU) ----------------
// Each (b, chunk) block sums its quarter of batch b's node range into part[b][chunk][c];
// k_reg combines the 4 partials deterministically (chunk 0->3) and divides by count.
// 4-chunk reorder of the serial sum: ~1e-6 relative, within tolerance.
__launch_bounds__(128)
__global__ void k_pool4(const float* __restrict__ agg, const float* __restrict__ st3,
                        const float* __restrict__ g3, const float* __restrict__ bt3,
                        const int* __restrict__ batch, float* __restrict__ part) {
  __shared__ int s_lo, s_hi;
  int b = blockIdx.x, chunk = blockIdx.y, tid = threadIdx.x;
  if (tid == 0) {
    int lo = 0, hi = NN;
    while (lo < hi) { int m = (lo + hi) >> 1; if (batch[m] < b) lo = m + 1; else hi = m; }
    s_lo = lo;
    hi = NN;
    while (lo < hi) { int m = (lo + hi) >> 1; if (batch[m] <= b) lo = m + 1; else hi = m; }
    s_hi = lo;
  }
  __syncthreads();
  int lo = s_lo, hi = s_hi;
  int q = (hi - lo + 3) >> 2;
  int st = lo + chunk * q;
  int en = min(st + q, hi);
  float sc, sh;
  bn_from_raw(st3[tid], st3[128 + tid], g3[tid], bt3[tid], sc, sh);
  float s = 0.f;
  for (int n = st; n < en; ++n) s += fmaxf(agg[(long)n * 128 + tid] * sc + sh, 0.f);
  part[b * 512 + chunk * 128 + tid] = s;
  if (chunk == 0 && tid == 0) part[262144 + b] = (float)(hi - lo);
}

// ---------------- fused regressor: per-sample 224 -> 512 -> 256 -> 1 ----------------
// cin[0..127] = mean-pool from k_pool4 partials (deterministic 4-way combine);
// cin[128..223] = conv max-pool from the merged conv grid.
__launch_bounds__(256)
__global__ void k_reg(const float* __restrict__ cbuf, const float* __restrict__ part,
                      const float* __restrict__ fw1, const float* __restrict__ fb1,
                      const float* __restrict__ fw2, const float* __restrict__ fb2,
                      const float* __restrict__ fw3, const float* __restrict__ fb3,
                      float* __restrict__ out) {
  __shared__ float cin[224];
  __shared__ float h1[512];
  __shared__ float h2[256];
  __shared__ float red[4];
  int b = blockIdx.x, t = threadIdx.x;
  if (t < 128) {
    float cnt = fmaxf(part[262144 + b], 1.0f);
    cin[t] = (part[b * 512 + t] + part[b * 512 + 128 + t] +
              part[b * 512 + 256 + t] + part[b * 512 + 384 + t]) / cnt;
  } else if (t < 224) {
    cin[t] = cbuf[b * 224 + t];
  }
  __syncthreads();
  {
    float a0 = fb1[t], a1 = fb1[t + 256];
    for (int ci = 0; ci < 224; ++ci) {
      float av = cin[ci];
      a0 += av * fw1[ci * 512 + t];
      a1 += av * fw1[ci * 512 + t + 256];
    }
    h1[t] = fmaxf(a0, 0.f);
    h1[t + 256] = fmaxf(a1, 0.f);
  }
  __syncthreads();
  {
    float a = fb2[t];
    for (int ci = 0; ci < 512; ++ci) a += h1[ci] * fw2[ci * 256 + t];
    h2[t] = fmaxf(a, 0.f);
  }
  __syncthreads();
  {
    float p = h2[t] * fw3[t];
#pragma unroll
    for (int off = 32; off > 0; off >>= 1) p += __shfl_down(p, off, 64);
    if ((t & 63) == 0) red[t >> 6] = p;
    __syncthreads();
    if (t == 0) out[b] = red[0] + red[1] + red[2] + red[3] + fb3[0];
  }
}

// ---------------- merged: protein conv tiles (blocks 0..4095) + gather128 (4096..8191) ----
// R8-proven: conv dur unchanged at ~111-125us while absorbing all of gather128's work
// (FETCH 10.7->37.5 GB). Conv body verbatim R5; gather body verbatim k_gbngather<128>.
__launch_bounds__(256, 3)
__global__ void conv_mfma(const int* __restrict__ seq, const float* __restrict__ e1g,
                          const float* __restrict__ cb1,
                          const unsigned short* __restrict__ wt2g, const float* __restrict__ cb2,
                          const unsigned short* __restrict__ wt3g, const float* __restrict__ cb3,
                          const float* __restrict__ gin, const float* __restrict__ dis,
                          const int* __restrict__ base, const unsigned short* __restrict__ csr_src,
                          const float* __restrict__ st2, const float* __restrict__ g2,
                          const float* __restrict__ bt2, float* __restrict__ gout,
                          float* __restrict__ outmax) {
  __shared__ __align__(16) unsigned short s_w[12288];
  __shared__ __align__(16) unsigned short s_c1[4864];   // 152 rows x 32 (XOR 16B-slot swizzle, key row&3)
  __shared__ __align__(16) unsigned short s_c2[9216];   // 144 rows x 64 (XOR 16B-slot swizzle, key row&7)
  __shared__ int s_tok[152];
  __shared__ int s_max[96];

  int tid = threadIdx.x;

  if (blockIdx.x >= 4096) {  // ---------------- gather128 part ----------------
    int t = (blockIdx.x - 4096) * 256 + tid;
    int n = t / 32;
    int c = (t % 32) * 4;
    float4 sum4 = *(const float4*)&st2[c];
    float4 ssq4 = *(const float4*)&st2[128 + c];
    float4 gg = *(const float4*)&g2[c];
    float4 bb = *(const float4*)&bt2[c];
    float4 sc4, sh4;
    bn_from_raw(sum4.x, ssq4.x, gg.x, bb.x, sc4.x, sh4.x);
    bn_from_raw(sum4.y, ssq4.y, gg.y, bb.y, sc4.y, sh4.y);
    bn_from_raw(sum4.z, ssq4.z, gg.z, bb.z, sc4.z, sh4.z);
    bn_from_raw(sum4.w, ssq4.w, gg.w, bb.w, sc4.w, sh4.w);
    float dn = dis[n];
    float s2 = dn * dn;
    float4 a = *(const float4*)&gin[(long)n * 128 + c];
    float4 acc;
    acc.x = fmaxf(a.x * sc4.x + sh4.x, 0.f) * s2;
    acc.y = fmaxf(a.y * sc4.y + sh4.y, 0.f) * s2;
    acc.z = fmaxf(a.z * sc4.z + sh4.z, 0.f) * s2;
    acc.w = fmaxf(a.w * sc4.w + sh4.w, 0.f) * s2;
    int b0 = base[n], b1 = base[n + 1];
    int sNext = (b0 < b1) ? csr_src[b0] : 0;
    for (int j = b0; j < b1; ++j) {
      int s = sNext;
      if (j + 1 < b1) sNext = csr_src[j + 1];
      float coef = dis[s] * dn;
      float4 vv = *(const float4*)&gin[(long)s * 128 + c];
      acc.x += fmaxf(vv.x * sc4.x + sh4.x, 0.f) * coef;
      acc.y += fmaxf(vv.y * sc4.y + sh4.y, 0.f) * coef;
      acc.z += fmaxf(vv.z * sc4.z + sh4.z, 0.f) * coef;
      acc.w += fmaxf(vv.w * sc4.w + sh4.w, 0.f) * coef;
    }
    *(float4*)&gout[(long)n * 128 + c] = acc;
    return;
  }

  // ---------------- conv tile part (verbatim R5 body) ----------------
  int tile = blockIdx.x >> 9;
  int b = blockIdx.x & 511;
  int t0 = tile * 128;

  if (tid < 96) s_max[tid] = 0;
  if (tid < 152) {
    int p = t0 - 6 + tid;
    s_tok[tid] = (p >= 0 && p < SL) ? seq[b * SL + p] : 0;
  }
  // zero s_c1 rows 144..151 (read-ahead region of conv2's 9th tile)
  if (tid < 128) ((int*)(s_c1 + 144 * 32))[tid] = 0;

  // phase 0: stage conv2 weights (full 384 rows x 32)
  {
#pragma unroll
    for (int c = 0; c < 6; ++c) {
      int ch = c * 256 + tid;
      int row = ch >> 2;
      *(bf16x8*)&s_w[row * 32 + (((row ^ ch) & 3) << 3)] = *(const bf16x8*)(wt2g + ch * 8);
    }
  }
  __syncthreads();  // barrier 1: s_tok + s_w(conv2) + c1 tail zeros ready

  int lane = tid & 63, wave = tid >> 6;
  int l15 = lane & 15, quad = lane >> 4;

  // ---- conv1 via table: rows 0..143, 32 ch each; 2 threads per row (16 ch per thread)
  {
    bool edge = (tile == 0) || (tile == 7);
#pragma unroll
    for (int pass = 0; pass < 2; ++pass) {
      int m = (pass == 0) ? (tid >> 1) : (128 + (tid >> 1));
      bool act = (pass == 0) || (tid < 32);
      if (act) {
        int co0 = (tid & 1) * 16;
        f32x4 a4[4];
#pragma unroll
        for (int q = 0; q < 4; ++q) a4[q] = *(const f32x4*)&cb1[co0 + q * 4];
#pragma unroll
        for (int kt = 0; kt < 4; ++kt) {
          const float* e = e1g + s_tok[m + kt] * 128 + kt * 32 + co0;
#pragma unroll
          for (int q = 0; q < 4; ++q) {
            f32x4 v = *(const f32x4*)&e[q * 4];
            a4[q][0] += v[0]; a4[q][1] += v[1]; a4[q][2] += v[2]; a4[q][3] += v[3];
          }
        }
        int l1 = t0 - 5 + m;
        bool ok = !edge || (l1 >= 0 && l1 < 999);   // uniform per thread (m fixed)
#pragma unroll
        for (int q = 0; q < 4; ++q) {
#pragma unroll
          for (int e2 = 0; e2 < 4; e2 += 2) {
            int co = co0 + q * 4 + e2;
            unsigned lo = ok ? (unsigned)f2b(fmaxf(a4[q][e2], 0.f)) : 0u;
            unsigned hi = ok ? (unsigned)f2b(fmaxf(a4[q][e2 + 1], 0.f)) : 0u;
            *(unsigned*)&s_c1[m * 32 + ((((co >> 3) ^ m) & 3) << 3) + (co & 7)] = lo | (hi << 16);
          }
        }
      }
    }
  }
  __syncthreads();  // barrier 2: s_c1 ready

  // ---- conv2: A from s_c1, B from s_w (staged phase 0)
  {
    int mt0 = wave, mt1 = wave + 4;
    f32x4 acc[2][4];
#pragma unroll
    for (int nt = 0; nt < 4; ++nt) {
      float bv = cb2[nt * 16 + l15];
      acc[0][nt] = (f32x4){bv, bv, bv, bv};
      acc[1][nt] = (f32x4){bv, bv, bv, bv};
    }
    for (int kt = 0; kt < 6; ++kt) {
      int r0 = mt0 * 16 + l15 + kt, r1 = mt1 * 16 + l15 + kt;
      bf16x8 a0 = *(const bf16x8*)&s_c1[r0 * 32 + (((quad ^ r0) & 3) << 3)];
      bf16x8 a1 = *(const bf16x8*)&s_c1[r1 * 32 + (((quad ^ r1) & 3) << 3)];
#pragma unroll
      for (int nt = 0; nt < 4; ++nt) {
        int wr = kt * 64 + nt * 16 + l15;
        bf16x8 bf = *(const bf16x8*)&s_w[wr * 32 + (((quad ^ wr) & 3) << 3)];
        acc[0][nt] = __builtin_amdgcn_mfma_f32_16x16x32_bf16(a0, bf, acc[0][nt], 0, 0, 0);
        acc[1][nt] = __builtin_amdgcn_mfma_f32_16x16x32_bf16(a1, bf, acc[1][nt], 0, 0, 0);
      }
    }
#pragma unroll
    for (int mb = 0; mb < 2; ++mb) {
      int mt = mb ? mt1 : mt0;
#pragma unroll
      for (int nt = 0; nt < 4; ++nt) {
        int co = nt * 16 + l15;
#pragma unroll
        for (int r = 0; r < 4; ++r) {
          int m = mt * 16 + quad * 4 + r;
          int l2 = t0 - 3 + m;
          unsigned short hv = f2b(fmaxf(acc[mb][nt][r], 0.f));
          s_c2[m * 64 + ((((co >> 3) ^ m) & 7) << 3) + (co & 7)] = (l2 >= 0 && l2 < 998) ? hv : (unsigned short)0;
        }
      }
    }
    if (wave == 0) {
      f32x4 acc8[4];
#pragma unroll
      for (int nt = 0; nt < 4; ++nt) {
        float bv = cb2[nt * 16 + l15];
        acc8[nt] = (f32x4){bv, bv, bv, bv};
      }
      for (int kt = 0; kt < 6; ++kt) {
        int r0 = 128 + l15 + kt;
        bf16x8 a0 = *(const bf16x8*)&s_c1[r0 * 32 + (((quad ^ r0) & 3) << 3)];
#pragma unroll
        for (int nt = 0; nt < 4; ++nt) {
          int wr = kt * 64 + nt * 16 + l15;
          bf16x8 bf = *(const bf16x8*)&s_w[wr * 32 + (((quad ^ wr) & 3) << 3)];
          acc8[nt] = __builtin_amdgcn_mfma_f32_16x16x32_bf16(a0, bf, acc8[nt], 0, 0, 0);
        }
      }
#pragma unroll
      for (int nt = 0; nt < 4; ++nt) {
        int co = nt * 16 + l15;
#pragma unroll
        for (int r = 0; r < 4; ++r) {
          int m = 128 + quad * 4 + r;
          int l2 = t0 - 3 + m;
          unsigned short hv = f2b(fmaxf(acc8[nt][r], 0.f));
          s_c2[m * 64 + ((((co >> 3) ^ m) & 7) << 3) + (co & 7)] = (l2 >= 0 && l2 < 998) ? hv : (unsigned short)0;
        }
      }
    }
  }

  // ---- stage conv3 kt=0 weights (dbuf 2 x [96][64])
  {
    bf16x8 w3t[3];
#pragma unroll
    for (int c = 0; c < 3; ++c) w3t[c] = *(const bf16x8*)(wt3g + (c * 256 + tid) * 8);
    __syncthreads();  // conv2 compute read s_w/s_c2 with no trailing barrier
#pragma unroll
    for (int c = 0; c < 3; ++c) {
      int ch = c * 256 + tid;
      int row = ch >> 3;
      *(bf16x8*)&s_w[row * 64 + (((row ^ ch) & 7) << 3)] = w3t[c];
    }
    __syncthreads();
  }

  // ---- conv3: kt double-buffered weights + fused max-pool
  {
    int mt0 = wave, mt1 = wave + 4;
    f32x4 acc[2][6];
#pragma unroll
    for (int nt = 0; nt < 6; ++nt) {
      float bv = cb3[nt * 16 + l15];
      acc[0][nt] = (f32x4){bv, bv, bv, bv};
      acc[1][nt] = (f32x4){bv, bv, bv, bv};
    }
    for (int kt = 0; kt < 8; ++kt) {
      bf16x8 w3t[3];
      if (kt < 7) {
#pragma unroll
        for (int c = 0; c < 3; ++c)
          w3t[c] = *(const bf16x8*)(wt3g + ((kt + 1) * 768 + c * 256 + tid) * 8);
      }
      int bo = (kt & 1) * 6144;
      int ra0 = mt0 * 16 + l15 + kt, ra1 = mt1 * 16 + l15 + kt;
#pragma unroll
      for (int cb = 0; cb < 2; ++cb) {
        bf16x8 a0 = *(const bf16x8*)&s_c2[ra0 * 64 + ((((cb * 4 + quad) ^ ra0) & 7) << 3)];
        bf16x8 a1 = *(const bf16x8*)&s_c2[ra1 * 64 + ((((cb * 4 + quad) ^ ra1) & 7) << 3)];
#pragma unroll
        for (int nt = 0; nt < 6; ++nt) {
          int wr = nt * 16 + l15;
          bf16x8 bf = *(const bf16x8*)&s_w[bo + wr * 64 + ((((cb * 4 + quad) ^ wr) & 7) << 3)];
          acc[0][nt] = __builtin_amdgcn_mfma_f32_16x16x32_bf16(a0, bf, acc[0][nt], 0, 0, 0);
          acc[1][nt] = __builtin_amdgcn_mfma_f32_16x16x32_bf16(a1, bf, acc[1][nt], 0, 0, 0);
        }
      }
      if (kt < 7) {
        int bo2 = 6144 - bo;
#pragma unroll
        for (int c = 0; c < 3; ++c) {
          int ch = c * 256 + tid;
          int row = ch >> 3;
          *(bf16x8*)&s_w[bo2 + row * 64 + (((row ^ ch) & 7) << 3)] = w3t[c];
        }
      }
      __syncthreads();
    }
#pragma unroll
    for (int nt = 0; nt < 6; ++nt) {
      int co = nt * 16 + l15;
      float mx = 0.f;
#pragma unroll
      for (int mb = 0; mb < 2; ++mb) {
        int mt = mb ? mt1 : mt0;
#pragma unroll
        for (int r = 0; r < 4; ++r) {
          int l3 = t0 + mt * 16 + quad * 4 + r;
          if (l3 < 997) mx = fmaxf(mx, acc[mb][nt][r]);
        }
      }
      atomicMax(&s_max[co], __float_as_int(mx));
    }
  }
  __syncthreads();
  if (tid < 96) atomicMax((int*)&outmax[b * 224 + 128 + tid], s_max[tid]);
}

extern "C" void kernel_launch(void* const* d_in, const int* in_sizes, int n_in,
                              void* d_out, int out_size, void* d_ws, size_t ws_size,
                              hipStream_t stream) {
  (void)in_sizes; (void)n_in; (void)out_size; (void)ws_size;
  const float* x = (const float*)d_in[0];
  const int* ei = (const int*)d_in[1];
  const int* batch = (const int*)d_in[2];
  const int* seq = (const int*)d_in[3];
  const float* W1 = (const float*)d_in[4];
  // b1/b2/b3 (d_in[5,9,13]) dropped: constant channel bias cancels in BatchNorm
  const float* g1 = (const float*)d_in[6];
  const float* bt1 = (const float*)d_in[7];
  const float* W2 = (const float*)d_in[8];
  const float* g2 = (const float*)d_in[10];
  const float* bt2 = (const float*)d_in[11];
  const float* W3 = (const float*)d_in[12];
  const float* g3 = (const float*)d_in[14];
  const float* bt3 = (const float*)d_in[15];
  const float* emb = (const float*)d_in[16];
  const float* ck1 = (const float*)d_in[17];
  const float* cb1 = (const float*)d_in[18];
  const float* ck2 = (const float*)d_in[19];
  const float* cb2 = (const float*)d_in[20];
  const float* ck3 = (const float*)d_in[21];
  const float* cb3 = (const float*)d_in[22];
  const float* fw1 = (const float*)d_in[23];
  const float* fb1 = (const float*)d_in[24];
  const float* fw2 = (const float*)d_in[25];
  const float* fb2 = (const float*)d_in[26];
  const float* fw3 = (const float*)d_in[27];
  const float* fb3 = (const float*)d_in[28];
  const int* src = ei;
  const int* dst = ei + NE;

  float* ws = (float*)d_ws;
  float* bufA = ws;                 // 32768*128 (16 MB)
  float* bufB = ws + 4194304;       // 32768*128 (16 MB); reused for pool partials after fc4-3
  float* dis = ws + 8388608;        // 32768
  // contiguous zero region: stats(656) | cbuf(114688) | degi(32768 ints)
  float* stats = ws + 8421376;
  float* cbuf = ws + 8422032;
  int* degi = (int*)(ws + 8536720);
  int* base = degi + NN;                  // 32769
  int* cursor = base + NN + 1;
  unsigned short* csr_src = (unsigned short*)(cursor + NN);  // 131072 u16
  unsigned short* emb_bf = (unsigned short*)(ws + 8700564);  // (unused region kept for layout)
  unsigned short* wt1 = emb_bf + 3328;                       // (unused)
  unsigned short* wt2 = wt1 + 16384;                         // 12288
  unsigned short* wt3 = wt2 + 12288;                         // 49152
  float* e1 = ws + 8741140;                                  // 3328 f32 conv1 table (16B-aligned)
  float* out = (float*)d_out;

  hipMemsetAsync(stats, 0, (656 + 114688 + 32768) * sizeof(float), stream);

  k_degprep<<<NE / 256, 256, 0, stream>>>(dst, degi, emb, ck1, ck2, ck3, wt2, wt3, e1);
  k_scan<<<1, 1024, 0, stream>>>(degi, base, cursor, dis);
  k_fill<<<NE / 256, 256, 0, stream>>>(src, dst, cursor, csr_src, NE);

  // ---- GNN chain (layer 1 + layer 2 up to stats)
  k_gfc1s<<<NN / 256, 256, 0, stream>>>(x, dis, base, csr_src, W1, bufA, stats);
  k_gbngather<64><<<NN * 16 / 256, 256, 0, stream>>>(bufA, dis, base, csr_src, stats, g1, bt1, bufB);
  k_fc4<128, 64, 4, false, false, true><<<1024, 256, 0, stream>>>(bufB, W2, nullptr, bufA, stats + 128, NN);

  // ---- merged: conv tiles (independent long pole) + gather128 (GNN layer-3 input)
  conv_mfma<<<8192, 256, 0, stream>>>(seq, e1, cb1, wt2, cb2, wt3, cb3,
                                      bufA, dis, base, csr_src, stats + 128, g2, bt2, bufB,
                                      cbuf);

  // ---- GNN layer-3 fc
  k_fc4<128, 128, 4, false, false, true><<<1024, 256, 0, stream>>>(bufB, W3, nullptr, bufA, stats + 384, NN);

  // ---- mean-pool (node-split 4x, partials into bufB which is now free) + fused regressor
  k_pool4<<<dim3(NB, 4), 128, 0, stream>>>(bufA, stats + 384, g3, bt3, batch, bufB);
  k_reg<<<NB, 256, 0, stream>>>(cbuf, bufB, fw1, fb1, fw2, fb2, fw3, fb3, out);
}